// Round 1
// baseline (5250.487 us; speedup 1.0000x reference)
//
#include <hip/hip_runtime.h>
#include <math.h>

#define NTOK 824     // B * G_VIS
#define GVIS 103
#define BB 8
#define GG 256
#define NPT 32
#define FEAT 273
#define C1 546       // 2*FEAT
#define ENCD 384
#define DMODEL 384
#define DIN 768
#define DSN 16
#define DTRN 24
#define LSEQ 103
#define EPSV 1e-5f

#define F_BIAS 1
#define F_GELU 2
#define F_SOFTPLUS 4
#define F_ACCUM 8

// ---------------- vis list + mask dtype detection ----------------
__global__ void vis_kernel(const void* maskp, int* vis, int* flag) {
  __shared__ int isInt;
  if (threadIdx.x == 0) {
    const unsigned char* bp = (const unsigned char*)maskp;
    int s = 0;
    for (int i = 0; i < BB * GG; ++i) if (i & 3) s += bp[i];
    isInt = (s == 0) ? 1 : 0;
    flag[0] = isInt;
  }
  __syncthreads();
  int b = threadIdx.x;
  if (b < BB) {
    const int* ip = (const int*)maskp;
    const unsigned char* bp = (const unsigned char*)maskp;
    int cnt = 0;
    for (int g = 0; g < GG && cnt < GVIS; ++g) {
      int mv = isInt ? ip[b*GG + g] : (int)bp[b*GG + g];
      if (mv == 0) { vis[b*GVIS + cnt] = g; ++cnt; }
    }
    for (; cnt < GVIS; ++cnt) vis[b*GVIS + cnt] = 0;
  }
}

__global__ void mask_out_kernel(const void* maskp, const int* flag, float* out) {
  int i = blockIdx.x * 256 + threadIdx.x;
  if (i >= BB * GG) return;
  int mv = flag[0] ? ((const int*)maskp)[i] : (int)((const unsigned char*)maskp)[i];
  out[NTOK * DMODEL + i] = mv ? 1.f : 0.f;
}

// ---------------- per-group feature max (fg) ----------------
__global__ __launch_bounds__(320) void fg_kernel(const float* __restrict__ nb,
                                                 const int* __restrict__ vis,
                                                 float* __restrict__ fg) {
  int gi = blockIdx.x;
  int c = threadIdx.x;
  if (c >= FEAT) return;
  int b = gi / GVIS;
  int g = vis[gi];
  const float* base = nb + (((size_t)b * GG + g) * NPT) * FEAT + c;
  float m = -3.4e38f;
  for (int n = 0; n < NPT; ++n) m = fmaxf(m, base[(size_t)n * FEAT]);
  fg[(size_t)gi * FEAT + c] = m;
}

// ---------------- shared GEMM core: C(64x64) = A(64xK) * B(64xK)^T ----------------
__device__ __forceinline__ void gemm_core(const float* aRow, const float* bRow, int K,
                                          float* As, float* Bs, int t,
                                          float (&acc)[4][4]) {
  const int tx = t & 15, ty = t >> 4;
  const int lk = (t & 3) * 4;
  const int lr = t >> 2;
  for (int k0 = 0; k0 < K; k0 += 16) {
#pragma unroll
    for (int j = 0; j < 4; ++j) {
      int k = k0 + lk + j;
      float av = 0.f, bv = 0.f;
      if (aRow && k < K) av = aRow[k];
      if (bRow && k < K) bv = bRow[k];
      As[(lk + j) * 68 + lr] = av;
      Bs[(lk + j) * 68 + lr] = bv;
    }
    __syncthreads();
#pragma unroll
    for (int kk = 0; kk < 16; ++kk) {
      float a[4], b[4];
#pragma unroll
      for (int i = 0; i < 4; ++i) a[i] = As[kk * 68 + ty * 4 + i];
#pragma unroll
      for (int j = 0; j < 4; ++j) b[j] = Bs[kk * 68 + tx * 4 + j];
#pragma unroll
      for (int i = 0; i < 4; ++i)
#pragma unroll
        for (int j = 0; j < 4; ++j)
          acc[i][j] = fmaf(a[i], b[j], acc[i][j]);
    }
    __syncthreads();
  }
}

// ---------------- plain GEMM with epilogue flags ----------------
template <int F>
__global__ __launch_bounds__(256) void gemm_plain(
    const float* __restrict__ A, int lda,
    const float* __restrict__ B, int ldb,
    const float* __restrict__ bias,
    float* __restrict__ C, int ldc,
    int M, int N, int K) {
  __shared__ float As[16 * 68];
  __shared__ float Bs[16 * 68];
  int t = threadIdx.x;
  int m0 = blockIdx.y * 64, n0 = blockIdx.x * 64;
  int lr = t >> 2;
  const float* aRow = (m0 + lr < M) ? A + (size_t)(m0 + lr) * lda : nullptr;
  const float* bRow = (n0 + lr < N) ? B + (size_t)(n0 + lr) * ldb : nullptr;
  float acc[4][4] = {{0.f}};
  gemm_core(aRow, bRow, K, As, Bs, t, acc);
  int tx = t & 15, ty = t >> 4;
#pragma unroll
  for (int i = 0; i < 4; ++i) {
    int m = m0 + ty * 4 + i;
    if (m >= M) continue;
#pragma unroll
    for (int j = 0; j < 4; ++j) {
      int n = n0 + tx * 4 + j;
      if (n >= N) continue;
      float v = acc[i][j];
      if (F & F_BIAS) v += bias[n];
      if (F & F_GELU) v = 0.5f * v * (1.f + erff(v * 0.70710678118f));
      if (F & F_SOFTPLUS) v = (v > 20.f) ? v : log1pf(expf(v));
      if (F & F_ACCUM) v += C[(size_t)m * ldc + n];
      C[(size_t)m * ldc + n] = v;
    }
  }
}

// ---------------- encoder stage 1: gathered A, BN+ReLU epilogue ----------------
__global__ __launch_bounds__(256) void gemm_enc1(
    const float* __restrict__ nb, const int* __restrict__ vis, int chunkG0,
    const float* __restrict__ Bw,  // c1w + FEAT (second-half channels), ldb = C1
    const float* __restrict__ bng, const float* __restrict__ bnb,
    const float* __restrict__ bnm, const float* __restrict__ bnv,
    const float* __restrict__ basep,
    float* __restrict__ f1) {
  __shared__ float As[16 * 68];
  __shared__ float Bs[16 * 68];
  int t = threadIdx.x;
  int m0 = blockIdx.y * 64, n0 = blockIdx.x * 64;
  int lr = t >> 2;
  int mrow = m0 + lr;                       // always < 6592
  int gi = chunkG0 + (mrow >> 5);
  int b = gi / GVIS;
  int g = vis[gi];
  const float* aRow = nb + (((size_t)b * GG + g) * NPT + (mrow & 31)) * FEAT;
  const float* bRow = (n0 + lr < C1) ? Bw + (size_t)(n0 + lr) * C1 : nullptr;
  float acc[4][4] = {{0.f}};
  gemm_core(aRow, bRow, FEAT, As, Bs, t, acc);
  int tx = t & 15, ty = t >> 4;
#pragma unroll
  for (int i = 0; i < 4; ++i) {
    int m = m0 + ty * 4 + i;
    int gie = chunkG0 + (m >> 5);
#pragma unroll
    for (int j = 0; j < 4; ++j) {
      int o = n0 + tx * 4 + j;
      if (o >= C1) continue;
      float sc = bng[o] * rsqrtf(bnv[o] + EPSV);
      float shf = bnb[o] - bnm[o] * sc;
      float v = acc[i][j] + basep[(size_t)gie * C1 + o];
      v = fmaxf(v * sc + shf, 0.f);
      f1[(size_t)m * C1 + o] = v;
    }
  }
}

// ---------------- encoder stage 2: GEMM + fused 32-row maxpool ----------------
__global__ __launch_bounds__(256) void gemm_enc2(
    const float* __restrict__ f1,
    const float* __restrict__ c2w, const float* __restrict__ c2b,
    float* __restrict__ hout, int chunkG0) {
  __shared__ float sh[64 * 68];
  float* As = sh;
  float* Bs = sh + 16 * 68;
  int t = threadIdx.x;
  int m0 = blockIdx.y * 64, n0 = blockIdx.x * 64;
  int lr = t >> 2;
  const float* aRow = f1 + (size_t)(m0 + lr) * C1;
  const float* bRow = c2w + (size_t)(n0 + lr) * C1;   // N=384 exact
  float acc[4][4] = {{0.f}};
  gemm_core(aRow, bRow, C1, As, Bs, t, acc);
  int tx = t & 15, ty = t >> 4;
#pragma unroll
  for (int i = 0; i < 4; ++i)
#pragma unroll
    for (int j = 0; j < 4; ++j)
      sh[(ty * 4 + i) * 68 + tx * 4 + j] = acc[i][j];
  __syncthreads();
  if (t < 128) {
    int grp = t >> 6, col = t & 63;
    float mx = -3.4e38f;
#pragma unroll
    for (int r = 0; r < 32; ++r) mx = fmaxf(mx, sh[(grp * 32 + r) * 68 + col]);
    int gi = chunkG0 + blockIdx.y * 2 + grp;
    int o = n0 + col;
    hout[(size_t)gi * ENCD + o] = mx + c2b[o];
  }
}

// ---------------- center gather ----------------
__global__ void gather_mc(const float* __restrict__ center, const int* __restrict__ vis,
                          float* __restrict__ mc) {
  int i = blockIdx.x * 256 + threadIdx.x;
  if (i >= NTOK * 3) return;
  int tok = i / 3, c = i % 3;
  int b = tok / GVIS;
  int g = vis[tok];
  mc[i] = center[((size_t)b * GG + g) * 3 + c];
}

// ---------------- layernorm (one wave per token) ----------------
__device__ __forceinline__ float wave_sum(float x) {
  for (int o = 32; o; o >>= 1) x += __shfl_xor(x, o);
  return x;
}

__global__ __launch_bounds__(64) void ln_kernel(
    const float* __restrict__ h, const float* __restrict__ res_in,
    float* __restrict__ res_out, float* __restrict__ hn,
    const float* __restrict__ w, const float* __restrict__ b, int add) {
  int tok = blockIdx.x, lane = threadIdx.x;
  const float* hr = h + (size_t)tok * DMODEL;
  float v[6];
#pragma unroll
  for (int j = 0; j < 6; ++j) {
    int c = lane + j * 64;
    float x = hr[c];
    if (add) x += res_in[(size_t)tok * DMODEL + c];
    v[j] = x;
  }
  float s = 0.f;
#pragma unroll
  for (int j = 0; j < 6; ++j) s += v[j];
  s = wave_sum(s);
  float mu = s * (1.f / DMODEL);
  float q = 0.f;
#pragma unroll
  for (int j = 0; j < 6; ++j) { float d = v[j] - mu; q += d * d; }
  q = wave_sum(q);
  float rstd = rsqrtf(q * (1.f / DMODEL) + EPSV);
#pragma unroll
  for (int j = 0; j < 6; ++j) {
    int c = lane + j * 64;
    res_out[(size_t)tok * DMODEL + c] = v[j];
    hn[(size_t)tok * DMODEL + c] = (v[j] - mu) * rstd * w[c] + b[c];
  }
}

__global__ __launch_bounds__(64) void final_kernel(
    const float* __restrict__ h, const float* __restrict__ res,
    const float* __restrict__ w1, const float* __restrict__ b1,
    const float* __restrict__ w2, const float* __restrict__ b2,
    float* __restrict__ out) {
  int tok = blockIdx.x, lane = threadIdx.x;
  float v[6];
#pragma unroll
  for (int j = 0; j < 6; ++j) {
    int c = lane + j * 64;
    v[j] = h[(size_t)tok * DMODEL + c] + res[(size_t)tok * DMODEL + c];
  }
  float s = 0.f;
#pragma unroll
  for (int j = 0; j < 6; ++j) s += v[j];
  s = wave_sum(s);
  float mu = s * (1.f / DMODEL);
  float q = 0.f;
#pragma unroll
  for (int j = 0; j < 6; ++j) { float d = v[j] - mu; q += d * d; }
  q = wave_sum(q);
  float rstd = rsqrtf(q * (1.f / DMODEL) + EPSV);
#pragma unroll
  for (int j = 0; j < 6; ++j) {
    int c = lane + j * 64;
    v[j] = (v[j] - mu) * rstd * w1[c] + b1[c];
  }
  // second LN
  s = 0.f;
#pragma unroll
  for (int j = 0; j < 6; ++j) s += v[j];
  s = wave_sum(s);
  mu = s * (1.f / DMODEL);
  q = 0.f;
#pragma unroll
  for (int j = 0; j < 6; ++j) { float d = v[j] - mu; q += d * d; }
  q = wave_sum(q);
  rstd = rsqrtf(q * (1.f / DMODEL) + EPSV);
#pragma unroll
  for (int j = 0; j < 6; ++j) {
    int c = lane + j * 64;
    out[(size_t)tok * DMODEL + c] = (v[j] - mu) * rstd * w2[c] + b2[c];
  }
}

// ---------------- causal depthwise conv (k=4) + silu ----------------
__global__ void conv_silu_kernel(const float* __restrict__ xz,
                                 const float* __restrict__ cw,
                                 const float* __restrict__ cb,
                                 float* __restrict__ xic) {
  int idx = blockIdx.x * 256 + threadIdx.x;
  if (idx >= NTOK * DIN) return;
  int c = idx % DIN, tok = idx / DIN;
  int b = tok / LSEQ, l = tok % LSEQ;
  const float* w = cw + (size_t)c * 4;
  float s = cb[c];
#pragma unroll
  for (int k = 0; k < 4; ++k) {
    int ls = l - 3 + k;
    if (ls >= 0) s = fmaf(w[k], xz[((size_t)(b * LSEQ + ls)) * (2 * DIN) + c], s);
  }
  xic[idx] = s / (1.f + expf(-s));
}

// ---------------- selective scan, fused D-skip and silu(z) gate ----------------
__global__ __launch_bounds__(256) void scan_kernel(
    const float* __restrict__ dt, const float* __restrict__ xic,
    const float* __restrict__ dbl, const float* __restrict__ xz,
    const float* __restrict__ alog, const float* __restrict__ Dp,
    float* __restrict__ ym) {
  int idx = blockIdx.x * 256 + threadIdx.x;
  if (idx >= BB * DIN) return;
  int d = idx % DIN, b = idx / DIN;
  float A[DSN];
#pragma unroll
  for (int s = 0; s < DSN; ++s) A[s] = -expf(alog[(size_t)d * DSN + s]);
  float hst[DSN];
#pragma unroll
  for (int s = 0; s < DSN; ++s) hst[s] = 0.f;
  float Dv = Dp[d];
  for (int l = 0; l < LSEQ; ++l) {
    size_t tok = (size_t)b * LSEQ + l;
    float dtv = dt[tok * DIN + d];
    float xiv = xic[tok * DIN + d];
    float dtxi = dtv * xiv;
    const float* bl = dbl + tok * 56;
    float y = 0.f;
#pragma unroll
    for (int s = 0; s < DSN; ++s) {
      float dA = expf(dtv * A[s]);
      hst[s] = fmaf(dA, hst[s], dtxi * bl[DTRN + s]);
      y = fmaf(hst[s], bl[DTRN + DSN + s], y);
    }
    float zv = xz[tok * (2 * DIN) + DIN + d];
    ym[tok * DIN + d] = (y + xiv * Dv) * (zv / (1.f + expf(-zv)));
  }
}

// ---------------- host launch ----------------
extern "C" void kernel_launch(void* const* d_in, const int* in_sizes, int n_in,
                              void* d_out, int out_size, void* d_ws, size_t ws_size,
                              hipStream_t stream) {
  const float* nb     = (const float*)d_in[0];
  const float* center = (const float*)d_in[1];
  const void*  maskp  = d_in[2];
  const float* c1w    = (const float*)d_in[3];
  const float* c1b    = (const float*)d_in[4];
  const float* bng    = (const float*)d_in[5];
  const float* bnb    = (const float*)d_in[6];
  const float* bnm    = (const float*)d_in[7];
  const float* bnv    = (const float*)d_in[8];
  const float* c2w    = (const float*)d_in[9];
  const float* c2b    = (const float*)d_in[10];
  const float* pw1    = (const float*)d_in[11];
  const float* pb1    = (const float*)d_in[12];
  const float* pw2    = (const float*)d_in[13];
  const float* pb2    = (const float*)d_in[14];
  const float* ipw    = (const float*)d_in[15];
  const float* cw     = (const float*)d_in[16];
  const float* cb     = (const float*)d_in[17];
  const float* xpw    = (const float*)d_in[18];
  const float* dpw    = (const float*)d_in[19];
  const float* dpb    = (const float*)d_in[20];
  const float* alog   = (const float*)d_in[21];
  const float* Dp     = (const float*)d_in[22];
  const float* opw    = (const float*)d_in[23];
  const float* lnw    = (const float*)d_in[24];
  const float* lnb    = (const float*)d_in[25];
  const float* nfw    = (const float*)d_in[26];
  const float* nfb    = (const float*)d_in[27];
  const float* n2w    = (const float*)d_in[28];
  const float* n2b    = (const float*)d_in[29];
  float* out = (float*)d_out;

  char* wsb = (char*)d_ws;
  size_t off = 0;
  auto alloc = [&](size_t nfl) -> void* {
    void* p = (void*)(wsb + off);
    off += ((nfl * 4 + 255) & ~(size_t)255);
    return p;
  };
  int*   vis   = (int*)alloc(832);
  int*   flag  = (int*)alloc(64);
  float* fg    = (float*)alloc((size_t)NTOK * FEAT);
  float* basep = (float*)alloc((size_t)NTOK * C1);
  float* f1    = (float*)alloc((size_t)6592 * C1);
  float* h     = (float*)alloc((size_t)NTOK * DMODEL);
  float* res   = (float*)alloc((size_t)NTOK * DMODEL);
  float* hn    = (float*)alloc((size_t)NTOK * DMODEL);
  float* mc    = (float*)alloc((size_t)NTOK * 3);
  float* t1    = (float*)alloc((size_t)NTOK * 128);
  float* xz    = (float*)alloc((size_t)NTOK * 2 * DIN);
  float* xic   = (float*)alloc((size_t)NTOK * DIN);
  float* dbl   = (float*)alloc((size_t)NTOK * 56);
  float* dtb   = (float*)alloc((size_t)NTOK * DIN);
  float* ym    = (float*)alloc((size_t)NTOK * DIN);

  // vis + mask echo
  vis_kernel<<<1, 64, 0, stream>>>(maskp, vis, flag);
  mask_out_kernel<<<8, 256, 0, stream>>>(maskp, flag, out);

  // encoder
  fg_kernel<<<NTOK, 320, 0, stream>>>(nb, vis, fg);
  gemm_plain<F_BIAS><<<dim3(9, 13), 256, 0, stream>>>(fg, FEAT, c1w, C1, c1b,
                                                      basep, C1, NTOK, C1, FEAT);
  for (int c = 0; c < 4; ++c) {
    gemm_enc1<<<dim3(9, 103), 256, 0, stream>>>(nb, vis, c * 206, c1w + FEAT,
                                                bng, bnb, bnm, bnv, basep, f1);
    gemm_enc2<<<dim3(6, 103), 256, 0, stream>>>(f1, c2w, c2b, h, c * 206);
  }

  // positional embedding, accumulated into h
  gather_mc<<<(NTOK * 3 + 255) / 256, 256, 0, stream>>>(center, vis, mc);
  gemm_plain<F_BIAS | F_GELU><<<dim3(2, 13), 256, 0, stream>>>(mc, 3, pw1, 3, pb1,
                                                               t1, 128, NTOK, 128, 3);
  gemm_plain<F_BIAS | F_ACCUM><<<dim3(6, 13), 256, 0, stream>>>(t1, 128, pw2, 128, pb2,
                                                                h, DMODEL, NTOK, DMODEL, 128);

  // 12 mamba layers
  for (int i = 0; i < 12; ++i) {
    ln_kernel<<<NTOK, 64, 0, stream>>>(h, res, res, hn, lnw + i * DMODEL,
                                       lnb + i * DMODEL, i > 0 ? 1 : 0);
    gemm_plain<0><<<dim3(24, 13), 256, 0, stream>>>(hn, DMODEL,
        ipw + (size_t)i * 2 * DIN * DMODEL, DMODEL, nullptr,
        xz, 2 * DIN, NTOK, 2 * DIN, DMODEL);
    conv_silu_kernel<<<(NTOK * DIN) / 256, 256, 0, stream>>>(
        xz, cw + (size_t)i * DIN * 4, cb + (size_t)i * DIN, xic);
    gemm_plain<0><<<dim3(1, 13), 256, 0, stream>>>(xic, DIN,
        xpw + (size_t)i * 56 * DIN, DIN, nullptr, dbl, 56, NTOK, 56, DIN);
    gemm_plain<F_BIAS | F_SOFTPLUS><<<dim3(12, 13), 256, 0, stream>>>(dbl, 56,
        dpw + (size_t)i * DIN * DTRN, DTRN, dpb + (size_t)i * DIN,
        dtb, DIN, NTOK, DIN, DTRN);
    scan_kernel<<<24, 256, 0, stream>>>(dtb, xic, dbl, xz,
        alog + (size_t)i * DIN * DSN, Dp + (size_t)i * DIN, ym);
    gemm_plain<0><<<dim3(6, 13), 256, 0, stream>>>(ym, DIN,
        opw + (size_t)i * DMODEL * DIN, DIN, nullptr, h, DMODEL, NTOK, DMODEL, DIN);
  }

  final_kernel<<<NTOK, 64, 0, stream>>>(h, res, nfw, nfb, n2w, n2b, out);
}

// Round 4
// 3369.859 us; speedup vs baseline: 1.5581x; 1.5581x over previous
//
#include <hip/hip_runtime.h>
#include <math.h>

#define GVIS 103
#define BB 8
#define GG 256
#define NPT 32
#define FEAT 273
#define C1 546
#define DMODEL 384
#define DIN 768
#define DSN 16
#define LSEQ 103
#define NTOK 824
#define EPSV 1e-5f
#define F1LD 552   // padded leading dim (halves) for f1 so rows stay 16B aligned

typedef __attribute__((ext_vector_type(8))) short s16x8;
typedef __attribute__((ext_vector_type(4))) float f32x4;

enum {
  EP_BIAS = 1, EP_GELU = 2, EP_SOFTPLUS = 4, EP_ACCUM = 8,
  EP_ENC1 = 16, EP_POOL = 32, EP_ABF16 = 64
};

__device__ __forceinline__ short f2bf(float f) {
  unsigned u = __builtin_bit_cast(unsigned, f);
  u += 0x7fffu + ((u >> 16) & 1u);
  return (short)(u >> 16);
}

struct GemmP {
  const float* A; int lda;
  const short* Abf;
  const float* B; int ldb;
  const float* bias;
  float* C; int ldc;
  short* f1;
  int M, N, K;
  const float* nb; const int* vis;
  const float* bng; const float* bnb; const float* bnm; const float* bnv;
  const float* basep;
};

// ---------------- MFMA GEMM: C[M,N] = A[M,K] * B[N,K]^T ----------------
// 128x128 tile, 4 waves (2x2 quadrants of 64x64), 16x16x32 bf16 MFMA.
template <int MODE>
__global__ __launch_bounds__(256) void gemm_mfma(GemmP p) {
  __shared__ short As[128 * 40];   // row stride 40 halves = 80B (16B-aligned, bank-friendly)
  __shared__ short Bsh[128 * 40];
  const int t = threadIdx.x;
  const int m0 = blockIdx.y * 128, n0 = blockIdx.x * 128;
  const int srow = t >> 1, skh = (t & 1) * 16;

  bool aValid;
  const bool bValid = (n0 + srow) < p.N;
  const float* aPtr = nullptr;
  const short* aPtrB = nullptr;
  if constexpr (MODE & EP_ENC1) {
    int mrow = m0 + srow;                 // M=26368 exact multiple of 128
    int gi = mrow >> 5;
    int b = gi / GVIS;
    int g = p.vis[gi];
    aPtr = p.nb + (((size_t)b * GG + g) * NPT + (mrow & 31)) * FEAT;
    aValid = true;
  } else if constexpr (MODE & EP_ABF16) {
    aValid = (m0 + srow) < p.M;
    aPtrB = aValid ? p.Abf + (size_t)(m0 + srow) * p.lda : nullptr;
  } else {
    aValid = (m0 + srow) < p.M;
    aPtr = aValid ? p.A + (size_t)(m0 + srow) * p.lda : nullptr;
  }
  const float* bPtr = bValid ? p.B + (size_t)(n0 + srow) * p.ldb : nullptr;
  const bool avec = (!(MODE & (EP_ENC1 | EP_ABF16))) && ((p.lda & 3) == 0);
  const bool bvec = ((p.ldb & 3) == 0);

  const int lane = t & 63, wave = t >> 6;
  const int wr = wave >> 1, wc = wave & 1;
  const int lrow = lane & 15, lk = (lane >> 4) * 8;

  f32x4 acc[4][4];
#pragma unroll
  for (int i = 0; i < 4; ++i)
#pragma unroll
    for (int j = 0; j < 4; ++j) acc[i][j] = f32x4{0.f, 0.f, 0.f, 0.f};

  for (int k0 = 0; k0 < p.K; k0 += 32) {
    // ---- stage A ----
    {
      s16x8 q0 = {}, q1 = {};
      if (aValid) {
        if constexpr (MODE & EP_ABF16) {
          if (k0 + skh + 15 < p.K) {
            q0 = *(const s16x8*)(aPtrB + k0 + skh);
            q1 = *(const s16x8*)(aPtrB + k0 + skh + 8);
          } else {
#pragma unroll
            for (int j = 0; j < 8; ++j) {
              int k = k0 + skh + j;
              q0[j] = (k < p.K) ? aPtrB[k] : (short)0;
              q1[j] = (k + 8 < p.K) ? aPtrB[k + 8] : (short)0;
            }
          }
        } else {
          float v[16];
          if (avec && (k0 + skh + 15 < p.K)) {
            f32x4 f0 = *(const f32x4*)(aPtr + k0 + skh);
            f32x4 f1v = *(const f32x4*)(aPtr + k0 + skh + 4);
            f32x4 f2v = *(const f32x4*)(aPtr + k0 + skh + 8);
            f32x4 f3v = *(const f32x4*)(aPtr + k0 + skh + 12);
#pragma unroll
            for (int j = 0; j < 4; ++j) {
              v[j] = f0[j]; v[j + 4] = f1v[j]; v[j + 8] = f2v[j]; v[j + 12] = f3v[j];
            }
          } else {
#pragma unroll
            for (int j = 0; j < 16; ++j) {
              int k = k0 + skh + j;
              v[j] = (k < p.K) ? aPtr[k] : 0.f;
            }
          }
#pragma unroll
          for (int j = 0; j < 8; ++j) { q0[j] = f2bf(v[j]); q1[j] = f2bf(v[j + 8]); }
        }
      }
      *(s16x8*)(As + srow * 40 + skh) = q0;
      *(s16x8*)(As + srow * 40 + skh + 8) = q1;
    }
    // ---- stage B ----
    {
      s16x8 q0 = {}, q1 = {};
      if (bValid) {
        float v[16];
        if (bvec && (k0 + skh + 15 < p.K)) {
          f32x4 f0 = *(const f32x4*)(bPtr + k0 + skh);
          f32x4 f1v = *(const f32x4*)(bPtr + k0 + skh + 4);
          f32x4 f2v = *(const f32x4*)(bPtr + k0 + skh + 8);
          f32x4 f3v = *(const f32x4*)(bPtr + k0 + skh + 12);
#pragma unroll
          for (int j = 0; j < 4; ++j) {
            v[j] = f0[j]; v[j + 4] = f1v[j]; v[j + 8] = f2v[j]; v[j + 12] = f3v[j];
          }
        } else {
#pragma unroll
          for (int j = 0; j < 16; ++j) {
            int k = k0 + skh + j;
            v[j] = (k < p.K) ? bPtr[k] : 0.f;
          }
        }
#pragma unroll
        for (int j = 0; j < 8; ++j) { q0[j] = f2bf(v[j]); q1[j] = f2bf(v[j + 8]); }
      }
      *(s16x8*)(Bsh + srow * 40 + skh) = q0;
      *(s16x8*)(Bsh + srow * 40 + skh + 8) = q1;
    }
    __syncthreads();
    s16x8 af[4], bfr[4];
#pragma unroll
    for (int f = 0; f < 4; ++f) {
      af[f] = *(const s16x8*)(As + (wr * 64 + f * 16 + lrow) * 40 + lk);
      bfr[f] = *(const s16x8*)(Bsh + (wc * 64 + f * 16 + lrow) * 40 + lk);
    }
#pragma unroll
    for (int i = 0; i < 4; ++i)
#pragma unroll
      for (int j = 0; j < 4; ++j)
        acc[i][j] = __builtin_amdgcn_mfma_f32_16x16x32_bf16(af[i], bfr[j], acc[i][j], 0, 0, 0);
    __syncthreads();
  }

  // ---------------- epilogues ----------------
  if constexpr (MODE & EP_POOL) {
    // enc2: maxpool over each 32-row point-group, +bias, write h[gi][o]
#pragma unroll
    for (int g2 = 0; g2 < 2; ++g2) {
#pragma unroll
      for (int fn = 0; fn < 4; ++fn) {
        float mx = -3.4e38f;
#pragma unroll
        for (int fm = 2 * g2; fm < 2 * g2 + 2; ++fm)
#pragma unroll
          for (int r = 0; r < 4; ++r) mx = fmaxf(mx, acc[fm][fn][r]);
        mx = fmaxf(mx, __shfl_xor(mx, 16));
        mx = fmaxf(mx, __shfl_xor(mx, 32));
        if ((lane >> 4) == 0) {
          int gi = (m0 + wr * 64 + g2 * 32) >> 5;
          int o = n0 + wc * 64 + fn * 16 + lane;
          p.C[(size_t)gi * p.ldc + o] = mx + p.bias[o];
        }
      }
    }
  } else if constexpr (MODE & EP_ENC1) {
#pragma unroll
    for (int fm = 0; fm < 4; ++fm) {
      int mbase = m0 + wr * 64 + fm * 16 + (lane >> 4) * 4;
#pragma unroll
      for (int fn = 0; fn < 4; ++fn) {
        int o = n0 + wc * 64 + fn * 16 + lrow;
        if (o >= p.N) continue;
        float sc = p.bng[o] * rsqrtf(p.bnv[o] + EPSV);
        float sh = p.bnb[o] - p.bnm[o] * sc;
#pragma unroll
        for (int r = 0; r < 4; ++r) {
          int mm = mbase + r;
          int gi = mm >> 5;
          float v = acc[fm][fn][r] + p.basep[(size_t)gi * C1 + o];
          v = fmaxf(v * sc + sh, 0.f);
          p.f1[(size_t)mm * F1LD + o] = f2bf(v);
        }
      }
    }
  } else {
#pragma unroll
    for (int fm = 0; fm < 4; ++fm) {
#pragma unroll
      for (int fn = 0; fn < 4; ++fn) {
        int o = n0 + wc * 64 + fn * 16 + lrow;
        if (o >= p.N) continue;
#pragma unroll
        for (int r = 0; r < 4; ++r) {
          int m = m0 + wr * 64 + fm * 16 + (lane >> 4) * 4 + r;
          if (m >= p.M) continue;
          float v = acc[fm][fn][r];
          if (MODE & EP_BIAS) v += p.bias[o];
          if (MODE & EP_GELU) v = 0.5f * v * (1.f + erff(v * 0.70710678118f));
          if (MODE & EP_SOFTPLUS) v = (v > 20.f) ? v : log1pf(expf(v));
          if (MODE & EP_ACCUM) v += p.C[(size_t)m * p.ldc + o];
          p.C[(size_t)m * p.ldc + o] = v;
        }
      }
    }
  }
}

// ---------------- vis list + mask dtype detection ----------------
__global__ void vis_kernel(const void* maskp, int* vis, int* flag) {
  __shared__ int isInt;
  if (threadIdx.x == 0) {
    const unsigned char* bp = (const unsigned char*)maskp;
    int s = 0;
    for (int i = 0; i < BB * GG; ++i) if (i & 3) s += bp[i];
    isInt = (s == 0) ? 1 : 0;
    flag[0] = isInt;
  }
  __syncthreads();
  int b = threadIdx.x;
  if (b < BB) {
    const int* ip = (const int*)maskp;
    const unsigned char* bp = (const unsigned char*)maskp;
    int cnt = 0;
    for (int g = 0; g < GG && cnt < GVIS; ++g) {
      int mv = isInt ? ip[b * GG + g] : (int)bp[b * GG + g];
      if (mv == 0) { vis[b * GVIS + cnt] = g; ++cnt; }
    }
    for (; cnt < GVIS; ++cnt) vis[b * GVIS + cnt] = 0;
  }
}

__global__ void mask_out_kernel(const void* maskp, const int* flag, float* out) {
  int i = blockIdx.x * 256 + threadIdx.x;
  if (i >= BB * GG) return;
  int mv = flag[0] ? ((const int*)maskp)[i] : (int)((const unsigned char*)maskp)[i];
  out[NTOK * DMODEL + i] = mv ? 1.f : 0.f;
}

// ---------------- per-group feature max (fg) ----------------
__global__ __launch_bounds__(320) void fg_kernel(const float* __restrict__ nb,
                                                 const int* __restrict__ vis,
                                                 float* __restrict__ fg) {
  int gi = blockIdx.x;
  int c = threadIdx.x;
  if (c >= FEAT) return;
  int b = gi / GVIS;
  int g = vis[gi];
  const float* base = nb + (((size_t)b * GG + g) * NPT) * FEAT + c;
  float m = -3.4e38f;
  for (int n = 0; n < NPT; ++n) m = fmaxf(m, base[(size_t)n * FEAT]);
  fg[(size_t)gi * FEAT + c] = m;
}

// ---------------- center gather ----------------
__global__ void gather_mc(const float* __restrict__ center, const int* __restrict__ vis,
                          float* __restrict__ mc) {
  int i = blockIdx.x * 256 + threadIdx.x;
  if (i >= NTOK * 3) return;
  int tok = i / 3, c = i % 3;
  int b = tok / GVIS;
  int g = vis[tok];
  mc[i] = center[((size_t)b * GG + g) * 3 + c];
}

// ---------------- layernorm (one wave per token) ----------------
__device__ __forceinline__ float wave_sum(float x) {
  for (int o = 32; o; o >>= 1) x += __shfl_xor(x, o);
  return x;
}

__global__ __launch_bounds__(64) void ln_kernel(
    const float* __restrict__ h, const float* __restrict__ res_in,
    float* __restrict__ res_out, float* __restrict__ hn,
    const float* __restrict__ w, const float* __restrict__ b, int add) {
  int tok = blockIdx.x, lane = threadIdx.x;
  const float* hr = h + (size_t)tok * DMODEL;
  float v[6];
#pragma unroll
  for (int j = 0; j < 6; ++j) {
    int c = lane + j * 64;
    float x = hr[c];
    if (add) x += res_in[(size_t)tok * DMODEL + c];
    v[j] = x;
  }
  float s = 0.f;
#pragma unroll
  for (int j = 0; j < 6; ++j) s += v[j];
  s = wave_sum(s);
  float mu = s * (1.f / DMODEL);
  float q = 0.f;
#pragma unroll
  for (int j = 0; j < 6; ++j) { float d = v[j] - mu; q += d * d; }
  q = wave_sum(q);
  float rstd = rsqrtf(q * (1.f / DMODEL) + EPSV);
#pragma unroll
  for (int j = 0; j < 6; ++j) {
    int c = lane + j * 64;
    res_out[(size_t)tok * DMODEL + c] = v[j];
    hn[(size_t)tok * DMODEL + c] = (v[j] - mu) * rstd * w[c] + b[c];
  }
}

__global__ __launch_bounds__(64) void final_kernel(
    const float* __restrict__ h, const float* __restrict__ res,
    const float* __restrict__ w1, const float* __restrict__ b1,
    const float* __restrict__ w2, const float* __restrict__ b2,
    float* __restrict__ out) {
  int tok = blockIdx.x, lane = threadIdx.x;
  float v[6];
#pragma unroll
  for (int j = 0; j < 6; ++j) {
    int c = lane + j * 64;
    v[j] = h[(size_t)tok * DMODEL + c] + res[(size_t)tok * DMODEL + c];
  }
  float s = 0.f;
#pragma unroll
  for (int j = 0; j < 6; ++j) s += v[j];
  s = wave_sum(s);
  float mu = s * (1.f / DMODEL);
  float q = 0.f;
#pragma unroll
  for (int j = 0; j < 6; ++j) { float d = v[j] - mu; q += d * d; }
  q = wave_sum(q);
  float rstd = rsqrtf(q * (1.f / DMODEL) + EPSV);
#pragma unroll
  for (int j = 0; j < 6; ++j) {
    int c = lane + j * 64;
    v[j] = (v[j] - mu) * rstd * w1[c] + b1[c];
  }
  s = 0.f;
#pragma unroll
  for (int j = 0; j < 6; ++j) s += v[j];
  s = wave_sum(s);
  mu = s * (1.f / DMODEL);
  q = 0.f;
#pragma unroll
  for (int j = 0; j < 6; ++j) { float d = v[j] - mu; q += d * d; }
  q = wave_sum(q);
  rstd = rsqrtf(q * (1.f / DMODEL) + EPSV);
#pragma unroll
  for (int j = 0; j < 6; ++j) {
    int c = lane + j * 64;
    out[(size_t)tok * DMODEL + c] = (v[j] - mu) * rstd * w2[c] + b2[c];
  }
}

// ---------------- causal depthwise conv (k=4) + silu ----------------
__global__ void conv_silu_kernel(const float* __restrict__ xz,
                                 const float* __restrict__ cw,
                                 const float* __restrict__ cb,
                                 float* __restrict__ xic) {
  int idx = blockIdx.x * 256 + threadIdx.x;
  if (idx >= NTOK * DIN) return;
  int c = idx % DIN, tok = idx / DIN;
  int b = tok / LSEQ, l = tok % LSEQ;
  const float* w = cw + (size_t)c * 4;
  float s = cb[c];
#pragma unroll
  for (int k = 0; k < 4; ++k) {
    int ls = l - 3 + k;
    if (ls >= 0) s = fmaf(w[k], xz[((size_t)(b * LSEQ + ls)) * (2 * DIN) + c], s);
  }
  xic[idx] = s / (1.f + expf(-s));
}

// ---------------- selective scan, state-parallel ----------------
__global__ __launch_bounds__(256) void scan_kernel2(
    const float* __restrict__ dt, const float* __restrict__ xic,
    const float* __restrict__ dbl, const float* __restrict__ xz,
    const float* __restrict__ alog, const float* __restrict__ Dp,
    float* __restrict__ ym) {
  int t = threadIdx.x;
  int s = t & 15, dloc = t >> 4;            // 16 states x 16 channels per block
  int b = blockIdx.x / 48, chunk = blockIdx.x % 48;
  int d = chunk * 16 + dloc;
  float Av = -expf(alog[(size_t)d * DSN + s]);
  float Dv = Dp[d];
  float h = 0.f;
  size_t tokbase = (size_t)b * LSEQ;
  for (int l = 0; l < LSEQ; ++l) {
    size_t tok = tokbase + l;
    float dtv = dt[tok * DIN + d];
    float xiv = xic[tok * DIN + d];
    float Bs = dbl[tok * 56 + 24 + s];
    float Cs = dbl[tok * 56 + 40 + s];
    float dA = expf(dtv * Av);
    h = fmaf(dA, h, dtv * xiv * Bs);
    float y = h * Cs;
    y += __shfl_xor(y, 1);
    y += __shfl_xor(y, 2);
    y += __shfl_xor(y, 4);
    y += __shfl_xor(y, 8);
    if (s == 0) {
      float zv = xz[tok * (2 * DIN) + DIN + d];
      ym[tok * DIN + d] = (y + xiv * Dv) * (zv / (1.f + expf(-zv)));
    }
  }
}

// ---------------- host launch ----------------
extern "C" void kernel_launch(void* const* d_in, const int* in_sizes, int n_in,
                              void* d_out, int out_size, void* d_ws, size_t ws_size,
                              hipStream_t stream) {
  const float* nb     = (const float*)d_in[0];
  const float* center = (const float*)d_in[1];
  const void*  maskp  = d_in[2];
  const float* c1w    = (const float*)d_in[3];
  const float* c1b    = (const float*)d_in[4];
  const float* bng    = (const float*)d_in[5];
  const float* bnb    = (const float*)d_in[6];
  const float* bnm    = (const float*)d_in[7];
  const float* bnv    = (const float*)d_in[8];
  const float* c2w    = (const float*)d_in[9];
  const float* c2b    = (const float*)d_in[10];
  const float* pw1    = (const float*)d_in[11];
  const float* pb1    = (const float*)d_in[12];
  const float* pw2    = (const float*)d_in[13];
  const float* pb2    = (const float*)d_in[14];
  const float* ipw    = (const float*)d_in[15];
  const float* cw     = (const float*)d_in[16];
  const float* cb     = (const float*)d_in[17];
  const float* xpw    = (const float*)d_in[18];
  const float* dpw    = (const float*)d_in[19];
  const float* dpb    = (const float*)d_in[20];
  const float* alog   = (const float*)d_in[21];
  const float* Dp     = (const float*)d_in[22];
  const float* opw    = (const float*)d_in[23];
  const float* lnw    = (const float*)d_in[24];
  const float* lnb    = (const float*)d_in[25];
  const float* nfw    = (const float*)d_in[26];
  const float* nfb    = (const float*)d_in[27];
  const float* n2w    = (const float*)d_in[28];
  const float* n2b    = (const float*)d_in[29];
  float* out = (float*)d_out;

  char* wsb = (char*)d_ws;
  size_t off = 0;
  auto alloc = [&](size_t bytes) -> void* {
    void* p = (void*)(wsb + off);
    off += ((bytes + 255) & ~(size_t)255);
    return p;
  };
  int*   vis   = (int*)alloc(NTOK * 4);
  int*   flag  = (int*)alloc(256);
  float* fg    = (float*)alloc((size_t)NTOK * FEAT * 4);
  float* basep = (float*)alloc((size_t)NTOK * C1 * 4);
  float* h     = (float*)alloc((size_t)NTOK * DMODEL * 4);
  float* res   = (float*)alloc((size_t)NTOK * DMODEL * 4);
  float* hn    = (float*)alloc((size_t)NTOK * DMODEL * 4);
  float* mc    = (float*)alloc((size_t)NTOK * 3 * 4);
  float* t1    = (float*)alloc((size_t)NTOK * 128 * 4);
  // region: f1 (encoder) overlaps mamba buffers (disjoint in time)
  char* region = (char*)alloc(26368ull * F1LD * 2);  // 29.1 MB dominates
  short* f1 = (short*)region;
  float* xz  = (float*)region;
  float* xic = (float*)(region + (size_t)NTOK * 1536 * 4);
  float* dbl = (float*)(region + (size_t)NTOK * (1536 + 768) * 4);
  float* dtb = (float*)(region + (size_t)NTOK * (1536 + 768 + 64) * 4);   // 56 padded to 64
  float* ym  = (float*)(region + (size_t)NTOK * (1536 + 768 + 64 + 768) * 4);

  vis_kernel<<<1, 64, 0, stream>>>(maskp, vis, flag);
  mask_out_kernel<<<8, 256, 0, stream>>>(maskp, flag, out);
  fg_kernel<<<NTOK, 320, 0, stream>>>(nb, vis, fg);

  auto mk = [&](const float* A, int lda, const float* B, int ldb, const float* bias,
                float* C, int ldc, int M, int N, int K) {
    GemmP p{};
    p.A = A; p.lda = lda; p.B = B; p.ldb = ldb; p.bias = bias;
    p.C = C; p.ldc = ldc; p.M = M; p.N = N; p.K = K;
    return p;
  };

  // basep = fg @ c1w_lo^T + c1b
  {
    GemmP p = mk(fg, FEAT, c1w, C1, c1b, basep, C1, NTOK, C1, FEAT);
    gemm_mfma<EP_BIAS><<<dim3(5, 7), 256, 0, stream>>>(p);
  }
  // enc1: f1 = relu(bn(nb_hi @ w_hi^T + basep))  -> bf16
  {
    GemmP p = mk(nullptr, 0, c1w + FEAT, C1, nullptr, nullptr, 0, 26368, C1, FEAT);
    p.nb = nb; p.vis = vis; p.bng = bng; p.bnb = bnb; p.bnm = bnm; p.bnv = bnv;
    p.basep = basep; p.f1 = f1;
    gemm_mfma<EP_ENC1><<<dim3(5, 206), 256, 0, stream>>>(p);
  }
  // enc2: h = maxpool32(f1 @ c2w^T) + c2b
  {
    GemmP p = mk(nullptr, F1LD, c2w, C1, c2b, h, DMODEL, 26368, DMODEL, C1);
    p.Abf = f1;
    gemm_mfma<EP_POOL | EP_ABF16><<<dim3(3, 206), 256, 0, stream>>>(p);
  }
  // positional embedding accumulated into h
  gather_mc<<<(NTOK * 3 + 255) / 256, 256, 0, stream>>>(center, vis, mc);
  {
    GemmP p = mk(mc, 3, pw1, 3, pb1, t1, 128, NTOK, 128, 3);
    gemm_mfma<EP_BIAS | EP_GELU><<<dim3(1, 7), 256, 0, stream>>>(p);
  }
  {
    GemmP p = mk(t1, 128, pw2, 128, pb2, h, DMODEL, NTOK, DMODEL, 128);
    gemm_mfma<EP_BIAS | EP_ACCUM><<<dim3(3, 7), 256, 0, stream>>>(p);
  }

  for (int i = 0; i < 12; ++i) {
    ln_kernel<<<NTOK, 64, 0, stream>>>(h, res, res, hn, lnw + i * DMODEL,
                                       lnb + i * DMODEL, i > 0 ? 1 : 0);
    {
      GemmP p = mk(hn, DMODEL, ipw + (size_t)i * 2 * DIN * DMODEL, DMODEL, nullptr,
                   xz, 2 * DIN, NTOK, 2 * DIN, DMODEL);
      gemm_mfma<0><<<dim3(12, 7), 256, 0, stream>>>(p);
    }
    conv_silu_kernel<<<(NTOK * DIN) / 256, 256, 0, stream>>>(
        xz, cw + (size_t)i * DIN * 4, cb + (size_t)i * DIN, xic);
    {
      GemmP p = mk(xic, DIN, xpw + (size_t)i * 56 * DIN, DIN, nullptr,
                   dbl, 56, NTOK, 56, DIN);
      gemm_mfma<0><<<dim3(1, 7), 256, 0, stream>>>(p);
    }
    {
      GemmP p = mk(dbl, 56, dpw + (size_t)i * DIN * 24, 24, dpb + (size_t)i * DIN,
                   dtb, DIN, NTOK, DIN, 24);
      gemm_mfma<EP_BIAS | EP_SOFTPLUS><<<dim3(6, 7), 256, 0, stream>>>(p);
    }
    scan_kernel2<<<384, 256, 0, stream>>>(dtb, xic, dbl, xz,
        alog + (size_t)i * DIN * DSN, Dp + (size_t)i * DIN, ym);
    {
      GemmP p = mk(ym, DIN, opw + (size_t)i * DMODEL * DIN, DIN, nullptr,
                   h, DMODEL, NTOK, DMODEL, DIN);
      gemm_mfma<0><<<dim3(3, 7), 256, 0, stream>>>(p);
    }
  }

  final_kernel<<<NTOK, 64, 0, stream>>>(h, res, nfw, nfb, n2w, n2b, out);
}

// Round 6
// 2728.892 us; speedup vs baseline: 1.9240x; 1.2349x over previous
//
#include <hip/hip_runtime.h>
#include <math.h>

#define GVIS 103
#define BB 8
#define GG 256
#define NPT 32
#define FEAT 273
#define C1 546
#define DMODEL 384
#define DIN 768
#define LSEQ 103
#define NTOK 824
#define EPSV 1e-5f
#define NBK 288          // padded K for point features (273->288)
#define F1K 576          // padded K for f1 (546->576)
#define CHG 412          // groups per encoder chunk
#define CHR (CHG * 32)   // rows per encoder chunk

typedef __attribute__((ext_vector_type(8))) short s16x8;
typedef __attribute__((ext_vector_type(4))) float f32x4;

enum {
  EP_BIAS = 1, EP_GELU = 2, EP_ACCUM = 4, EP_ENC1 = 8, EP_POOL = 16,
  EP_ABF16 = 32, EP_BBF16 = 64, EP_CONV = 128
};

__device__ __forceinline__ short f2bf(float f) {
  unsigned u = __builtin_bit_cast(unsigned, f);
  u += 0x7fffu + ((u >> 16) & 1u);
  return (short)(u >> 16);
}

struct GemmP {
  const float* A; int lda;
  const short* Abf;
  const float* B; int ldb;
  const short* Bbf;
  const float* bias;
  float* C; int ldc;
  short* f1;
  int M, N, K, Kp, g0;
  const float* bng; const float* bnb; const float* bnm; const float* bnv;
  const float* basep;
  const float* cw; const float* cb; float* xic;
};

// ---------------- MFMA GEMM: C[M,N] = A[M,K] * B[N,K]^T ----------------
// TM=128: 4 waves as 2x2 (64x64 each). TM=64: 4 waves as 1x4 (64x32 each).
template <int MODE, int TM>
__global__ __launch_bounds__(256) void gemm_mfma(GemmP p) {
  __shared__ short As[TM * 40];
  __shared__ short Bs[128 * 40];
  constexpr int WC = (TM == 128) ? 2 : 4;
  constexpr int NF = 128 / (WC * 16);
  const int t = threadIdx.x;
  const int m0 = blockIdx.y * TM, n0 = blockIdx.x * 128;
  const int srow = t >> 1, skh = (t & 1) * 16;
  const int lane = t & 63, wave = t >> 6;
  const int wr = wave / WC, wc = wave % WC;
  const int lrow = lane & 15, lk = (lane >> 4) * 8;

  const bool aRowIn = (TM == 128) ? true : (t < 128);
  const int arow = m0 + srow;
  const bool aValid = aRowIn && (arow < p.M);
  const bool bValid = (n0 + srow) < p.N;
  const float* aPtr = nullptr; const short* aPtrB = nullptr;
  if constexpr (MODE & EP_ABF16) { if (aValid) aPtrB = p.Abf + (size_t)arow * p.lda; }
  else if constexpr (!(MODE & EP_CONV)) { if (aValid) aPtr = p.A + (size_t)arow * p.lda; }
  const float* bPtrF = nullptr; const short* bPtrB = nullptr;
  if constexpr (MODE & EP_BBF16) { if (bValid) bPtrB = p.Bbf + (size_t)(n0 + srow) * p.ldb; }
  else { if (bValid) bPtrF = p.B + (size_t)(n0 + srow) * p.ldb; }
  const bool avec = ((p.lda & 3) == 0) && (p.K == p.Kp);
  const bool bvec = ((p.ldb & 3) == 0) && (p.K == p.Kp);

  int cb_b = 0, cb_l = 0;
  if constexpr (MODE & EP_CONV) { cb_b = arow / LSEQ; cb_l = arow - cb_b * LSEQ; }

  f32x4 acc[4][NF];
#pragma unroll
  for (int i = 0; i < 4; ++i)
#pragma unroll
    for (int j = 0; j < NF; ++j) acc[i][j] = f32x4{0.f, 0.f, 0.f, 0.f};

  for (int k0 = 0; k0 < p.Kp; k0 += 32) {
    // ---- stage A ----
    if (aRowIn) {
      s16x8 q0 = {}, q1 = {};
      if (aValid) {
        if constexpr (MODE & EP_CONV) {
          const int c0 = k0 + skh;
          f32x4 cwv[16];
#pragma unroll
          for (int j = 0; j < 16; ++j) cwv[j] = *(const f32x4*)(p.cw + (size_t)(c0 + j) * 4);
          float sv[16];
#pragma unroll
          for (int j = 0; j < 16; ++j) sv[j] = p.cb[c0 + j];
#pragma unroll
          for (int kk = 0; kk < 4; ++kk) {
            int ls = cb_l - 3 + kk;
            if (ls < 0) continue;
            const float* xr = p.A + (size_t)(cb_b * LSEQ + ls) * p.lda + c0;
#pragma unroll
            for (int q = 0; q < 4; ++q) {
              f32x4 xv = *(const f32x4*)(xr + 4 * q);
#pragma unroll
              for (int e = 0; e < 4; ++e)
                sv[4 * q + e] = fmaf(cwv[4 * q + e][kk], xv[e], sv[4 * q + e]);
            }
          }
#pragma unroll
          for (int j = 0; j < 16; ++j) {
            float val = sv[j] / (1.f + expf(-sv[j]));
            p.xic[(size_t)arow * DIN + c0 + j] = val;
            short bv = f2bf(val);
            if (j < 8) q0[j] = bv; else q1[j - 8] = bv;
          }
        } else if constexpr (MODE & EP_ABF16) {
          q0 = *(const s16x8*)(aPtrB + k0 + skh);
          q1 = *(const s16x8*)(aPtrB + k0 + skh + 8);
        } else {
          float v[16];
          if (avec) {
            f32x4 f0 = *(const f32x4*)(aPtr + k0 + skh);
            f32x4 f1v = *(const f32x4*)(aPtr + k0 + skh + 4);
            f32x4 f2v = *(const f32x4*)(aPtr + k0 + skh + 8);
            f32x4 f3v = *(const f32x4*)(aPtr + k0 + skh + 12);
#pragma unroll
            for (int j = 0; j < 4; ++j) {
              v[j] = f0[j]; v[j + 4] = f1v[j]; v[j + 8] = f2v[j]; v[j + 12] = f3v[j];
            }
          } else {
#pragma unroll
            for (int j = 0; j < 16; ++j) {
              int k = k0 + skh + j;
              v[j] = (k < p.K) ? aPtr[k] : 0.f;
            }
          }
#pragma unroll
          for (int j = 0; j < 8; ++j) { q0[j] = f2bf(v[j]); q1[j] = f2bf(v[j + 8]); }
        }
      }
      *(s16x8*)(As + srow * 40 + skh) = q0;
      *(s16x8*)(As + srow * 40 + skh + 8) = q1;
    }
    // ---- stage B ----
    {
      s16x8 q0 = {}, q1 = {};
      if (bValid) {
        if constexpr (MODE & EP_BBF16) {
          q0 = *(const s16x8*)(bPtrB + k0 + skh);
          q1 = *(const s16x8*)(bPtrB + k0 + skh + 8);
        } else {
          float v[16];
          if (bvec) {
            f32x4 f0 = *(const f32x4*)(bPtrF + k0 + skh);
            f32x4 f1v = *(const f32x4*)(bPtrF + k0 + skh + 4);
            f32x4 f2v = *(const f32x4*)(bPtrF + k0 + skh + 8);
            f32x4 f3v = *(const f32x4*)(bPtrF + k0 + skh + 12);
#pragma unroll
            for (int j = 0; j < 4; ++j) {
              v[j] = f0[j]; v[j + 4] = f1v[j]; v[j + 8] = f2v[j]; v[j + 12] = f3v[j];
            }
          } else {
#pragma unroll
            for (int j = 0; j < 16; ++j) {
              int k = k0 + skh + j;
              v[j] = (k < p.K) ? bPtrF[k] : 0.f;
            }
          }
#pragma unroll
          for (int j = 0; j < 8; ++j) { q0[j] = f2bf(v[j]); q1[j] = f2bf(v[j + 8]); }
        }
      }
      *(s16x8*)(Bs + srow * 40 + skh) = q0;
      *(s16x8*)(Bs + srow * 40 + skh + 8) = q1;
    }
    __syncthreads();
    s16x8 af[4], bfr[NF];
#pragma unroll
    for (int f = 0; f < 4; ++f)
      af[f] = *(const s16x8*)(As + (wr * 64 + f * 16 + lrow) * 40 + lk);
#pragma unroll
    for (int f = 0; f < NF; ++f)
      bfr[f] = *(const s16x8*)(Bs + (wc * (NF * 16) + f * 16 + lrow) * 40 + lk);
#pragma unroll
    for (int i = 0; i < 4; ++i)
#pragma unroll
      for (int j = 0; j < NF; ++j)
        acc[i][j] = __builtin_amdgcn_mfma_f32_16x16x32_bf16(af[i], bfr[j], acc[i][j], 0, 0, 0);
    __syncthreads();
  }

  // ---------------- epilogues ----------------
  if constexpr (MODE & EP_POOL) {
#pragma unroll
    for (int g2 = 0; g2 < 2; ++g2) {
#pragma unroll
      for (int fn = 0; fn < NF; ++fn) {
        float mx = -3.4e38f;
#pragma unroll
        for (int fm = 2 * g2; fm < 2 * g2 + 2; ++fm)
#pragma unroll
          for (int r = 0; r < 4; ++r) mx = fmaxf(mx, acc[fm][fn][r]);
        mx = fmaxf(mx, __shfl_xor(mx, 16));
        mx = fmaxf(mx, __shfl_xor(mx, 32));
        if ((lane >> 4) == 0) {
          int gi = p.g0 + ((m0 + wr * 64 + g2 * 32) >> 5);
          int o = n0 + wc * (NF * 16) + fn * 16 + lane;
          p.C[(size_t)gi * p.ldc + o] = mx + p.bias[o];
        }
      }
    }
  } else if constexpr (MODE & EP_ENC1) {
#pragma unroll
    for (int fm = 0; fm < 4; ++fm) {
      int mbase = m0 + wr * 64 + fm * 16 + (lane >> 4) * 4;
#pragma unroll
      for (int fn = 0; fn < NF; ++fn) {
        int o = n0 + wc * (NF * 16) + fn * 16 + lrow;
        if (o >= F1K) continue;
        if (o < C1) {
          float sc = p.bng[o] * rsqrtf(p.bnv[o] + EPSV);
          float sh = p.bnb[o] - p.bnm[o] * sc;
#pragma unroll
          for (int r = 0; r < 4; ++r) {
            int mm = mbase + r;
            int gi = p.g0 + (mm >> 5);
            float v = acc[fm][fn][r] + p.basep[(size_t)gi * C1 + o];
            p.f1[(size_t)mm * F1K + o] = f2bf(fmaxf(v * sc + sh, 0.f));
          }
        } else {
#pragma unroll
          for (int r = 0; r < 4; ++r) p.f1[(size_t)(mbase + r) * F1K + o] = 0;
        }
      }
    }
  } else {
#pragma unroll
    for (int fm = 0; fm < 4; ++fm) {
#pragma unroll
      for (int fn = 0; fn < NF; ++fn) {
        int o = n0 + wc * (NF * 16) + fn * 16 + lrow;
        if (o >= p.N) continue;
#pragma unroll
        for (int r = 0; r < 4; ++r) {
          int m = m0 + wr * 64 + fm * 16 + (lane >> 4) * 4 + r;
          if (m >= p.M) continue;
          float v = acc[fm][fn][r];
          if (MODE & EP_BIAS) v += p.bias[o];
          if (MODE & EP_GELU) v = 0.5f * v * (1.f + erff(v * 0.70710678118f));
          if (MODE & EP_ACCUM) v += p.C[(size_t)m * p.ldc + o];
          p.C[(size_t)m * p.ldc + o] = v;
        }
      }
    }
  }
}

// ---------------- weight convert/pad fp32 -> bf16 ----------------
__global__ void cvt_pad(const float* __restrict__ src, int srcld, int colOff,
                        short* __restrict__ dst, int nrows, int Kv, int Kp) {
  int idx = blockIdx.x * 256 + threadIdx.x;
  if (idx >= nrows * Kp) return;
  int r = idx / Kp, k = idx - r * Kp;
  dst[idx] = (k < Kv) ? f2bf(src[(size_t)r * srcld + colOff + k]) : (short)0;
}

// ---------------- vis list + mask dtype detection ----------------
__global__ void vis_kernel(const void* maskp, int* vis, int* flag) {
  __shared__ int isInt;
  if (threadIdx.x == 0) {
    const unsigned char* bp = (const unsigned char*)maskp;
    int s = 0;
    for (int i = 0; i < BB * GG; ++i) if (i & 3) s += bp[i];
    isInt = (s == 0) ? 1 : 0;
    flag[0] = isInt;
  }
  __syncthreads();
  int b = threadIdx.x;
  if (b < BB) {
    const int* ip = (const int*)maskp;
    const unsigned char* bp = (const unsigned char*)maskp;
    int cnt = 0;
    for (int g = 0; g < GG && cnt < GVIS; ++g) {
      int mv = isInt ? ip[b * GG + g] : (int)bp[b * GG + g];
      if (mv == 0) { vis[b * GVIS + cnt] = g; ++cnt; }
    }
    for (; cnt < GVIS; ++cnt) vis[b * GVIS + cnt] = 0;
  }
}

__global__ void mask_out_kernel(const void* maskp, const int* flag, float* out) {
  int i = blockIdx.x * 256 + threadIdx.x;
  if (i >= BB * GG) return;
  int mv = flag[0] ? ((const int*)maskp)[i] : (int)((const unsigned char*)maskp)[i];
  out[NTOK * DMODEL + i] = mv ? 1.f : 0.f;
}

// ---------------- gather visible groups -> compact bf16 + per-group max ----------------
__global__ __launch_bounds__(320) void gather_fg(const float* __restrict__ nb,
                                                 const int* __restrict__ vis, int g0,
                                                 short* __restrict__ nbg,
                                                 float* __restrict__ fg) {
  int gl = blockIdx.x;
  int gi = g0 + gl;
  int c = threadIdx.x;
  if (c >= NBK) return;
  int b = gi / GVIS;
  int g = vis[gi];
  size_t base = ((size_t)(b * GG + g)) * NPT * FEAT;
  size_t orow = (size_t)gl * 32;
  if (c < FEAT) {
    float mx = -3.4e38f;
#pragma unroll 4
    for (int r = 0; r < 32; ++r) {
      float v = nb[base + (size_t)r * FEAT + c];
      mx = fmaxf(mx, v);
      nbg[(orow + r) * NBK + c] = f2bf(v);
    }
    fg[(size_t)gi * NBK + c] = mx;
  } else {
    for (int r = 0; r < 32; ++r) nbg[(orow + r) * NBK + c] = 0;
    fg[(size_t)gi * NBK + c] = 0.f;
  }
}

// ---------------- center gather ----------------
__global__ void gather_mc(const float* __restrict__ center, const int* __restrict__ vis,
                          float* __restrict__ mc) {
  int i = blockIdx.x * 256 + threadIdx.x;
  if (i >= NTOK * 3) return;
  int tok = i / 3, c = i - tok * 3;
  int b = tok / GVIS;
  int g = vis[tok];
  mc[i] = center[((size_t)b * GG + g) * 3 + c];
}

// ---------------- layernorm: 4 tokens/block ----------------
__device__ __forceinline__ float wave_sum(float x) {
  for (int o = 32; o; o >>= 1) x += __shfl_xor(x, o);
  return x;
}

__global__ __launch_bounds__(256) void ln4_kernel(
    const float* __restrict__ h, const float* __restrict__ res_in,
    float* __restrict__ res_out, float* __restrict__ hn,
    const float* __restrict__ w, const float* __restrict__ b, int add) {
  int tok = blockIdx.x * 4 + (threadIdx.x >> 6);
  int lane = threadIdx.x & 63;
  if (tok >= NTOK) return;
  const float* hr = h + (size_t)tok * DMODEL;
  float v[6];
#pragma unroll
  for (int j = 0; j < 6; ++j) {
    int c = lane + j * 64;
    float x = hr[c];
    if (add) x += res_in[(size_t)tok * DMODEL + c];
    v[j] = x;
  }
  float s = 0.f;
#pragma unroll
  for (int j = 0; j < 6; ++j) s += v[j];
  s = wave_sum(s);
  float mu = s * (1.f / DMODEL);
  float q = 0.f;
#pragma unroll
  for (int j = 0; j < 6; ++j) { float d = v[j] - mu; q += d * d; }
  q = wave_sum(q);
  float rstd = rsqrtf(q * (1.f / DMODEL) + EPSV);
#pragma unroll
  for (int j = 0; j < 6; ++j) {
    int c = lane + j * 64;
    res_out[(size_t)tok * DMODEL + c] = v[j];
    hn[(size_t)tok * DMODEL + c] = (v[j] - mu) * rstd * w[c] + b[c];
  }
}

__global__ __launch_bounds__(64) void final_kernel(
    const float* __restrict__ h, const float* __restrict__ res,
    const float* __restrict__ w1, const float* __restrict__ b1,
    const float* __restrict__ w2, const float* __restrict__ b2,
    float* __restrict__ out) {
  int tok = blockIdx.x, lane = threadIdx.x;
  float v[6];
#pragma unroll
  for (int j = 0; j < 6; ++j) {
    int c = lane + j * 64;
    v[j] = h[(size_t)tok * DMODEL + c] + res[(size_t)tok * DMODEL + c];
  }
  float s = 0.f;
#pragma unroll
  for (int j = 0; j < 6; ++j) s += v[j];
  s = wave_sum(s);
  float mu = s * (1.f / DMODEL);
  float q = 0.f;
#pragma unroll
  for (int j = 0; j < 6; ++j) { float d = v[j] - mu; q += d * d; }
  q = wave_sum(q);
  float rstd = rsqrtf(q * (1.f / DMODEL) + EPSV);
#pragma unroll
  for (int j = 0; j < 6; ++j) {
    int c = lane + j * 64;
    v[j] = (v[j] - mu) * rstd * w1[c] + b1[c];
  }
  s = 0.f;
#pragma unroll
  for (int j = 0; j < 6; ++j) s += v[j];
  s = wave_sum(s);
  mu = s * (1.f / DMODEL);
  q = 0.f;
#pragma unroll
  for (int j = 0; j < 6; ++j) { float d = v[j] - mu; q += d * d; }
  q = wave_sum(q);
  rstd = rsqrtf(q * (1.f / DMODEL) + EPSV);
#pragma unroll
  for (int j = 0; j < 6; ++j) {
    int c = lane + j * 64;
    out[(size_t)tok * DMODEL + c] = (v[j] - mu) * rstd * w2[c] + b2[c];
  }
}

// ---------------- fused dt_proj + selective scan (LDS-resident) ----------------
__global__ __launch_bounds__(256) void scan_fused(
    const float* __restrict__ dbl, const float* __restrict__ xic,
    const float* __restrict__ xz, const float* __restrict__ dpw,
    const float* __restrict__ dpb, const float* __restrict__ alog,
    const float* __restrict__ Dp, float* __restrict__ ym) {
  __shared__ float sdbl[LSEQ][56];
  __shared__ float sdt[LSEQ][16];
  __shared__ float sxi[LSEQ][16];
  __shared__ float sz[LSEQ][16];
  __shared__ float sy[LSEQ][16];
  int t = threadIdx.x;
  int b = blockIdx.x / 48, chunk = blockIdx.x % 48;
  int d0 = chunk * 16;
  for (int u = t; u < LSEQ * 56; u += 256) {
    int l = u / 56, cc = u - l * 56;
    sdbl[l][cc] = dbl[((size_t)b * LSEQ + l) * 56 + cc];
  }
  for (int u = t; u < LSEQ * 16; u += 256) {
    int l = u >> 4, dl = u & 15;
    sxi[l][dl] = xic[((size_t)b * LSEQ + l) * DIN + d0 + dl];
    sz[l][dl] = xz[((size_t)b * LSEQ + l) * (2 * DIN) + DIN + d0 + dl];
  }
  __syncthreads();
  for (int u = t; u < LSEQ * 16; u += 256) {
    int l = u >> 4, dl = u & 15;
    const float* wp = dpw + (size_t)(d0 + dl) * 24;
    float s = dpb[d0 + dl];
#pragma unroll
    for (int kk = 0; kk < 24; ++kk) s = fmaf(wp[kk], sdbl[l][kk], s);
    sdt[l][dl] = (s > 20.f) ? s : log1pf(expf(s));
  }
  __syncthreads();
  int s = t & 15, dloc = t >> 4;
  int d = d0 + dloc;
  float Av = -expf(alog[(size_t)d * 16 + s]);
  float Dv = Dp[d];
  float h = 0.f;
  for (int l = 0; l < LSEQ; ++l) {
    float dtv = sdt[l][dloc];
    float xiv = sxi[l][dloc];
    float hB = sdbl[l][24 + s], hC = sdbl[l][40 + s];
    h = fmaf(expf(dtv * Av), h, dtv * xiv * hB);
    float y = h * hC;
    y += __shfl_xor(y, 1);
    y += __shfl_xor(y, 2);
    y += __shfl_xor(y, 4);
    y += __shfl_xor(y, 8);
    if (s == 0) {
      float zv = sz[l][dloc];
      sy[l][dloc] = (y + xiv * Dv) * (zv / (1.f + expf(-zv)));
    }
  }
  __syncthreads();
  for (int u = t; u < LSEQ * 16; u += 256)
    ym[((size_t)b * LSEQ + (u >> 4)) * DIN + d0 + (u & 15)] = sy[u >> 4][u & 15];
}

// ---------------- host launch ----------------
extern "C" void kernel_launch(void* const* d_in, const int* in_sizes, int n_in,
                              void* d_out, int out_size, void* d_ws, size_t ws_size,
                              hipStream_t stream) {
  const float* nb     = (const float*)d_in[0];
  const float* center = (const float*)d_in[1];
  const void*  maskp  = d_in[2];
  const float* c1w    = (const float*)d_in[3];
  const float* c1b    = (const float*)d_in[4];
  const float* bng    = (const float*)d_in[5];
  const float* bnb    = (const float*)d_in[6];
  const float* bnm    = (const float*)d_in[7];
  const float* bnv    = (const float*)d_in[8];
  const float* c2w    = (const float*)d_in[9];
  const float* c2b    = (const float*)d_in[10];
  const float* pw1    = (const float*)d_in[11];
  const float* pb1    = (const float*)d_in[12];
  const float* pw2    = (const float*)d_in[13];
  const float* pb2    = (const float*)d_in[14];
  const float* ipw    = (const float*)d_in[15];
  const float* cw     = (const float*)d_in[16];
  const float* cb     = (const float*)d_in[17];
  const float* xpw    = (const float*)d_in[18];
  const float* dpw    = (const float*)d_in[19];
  const float* dpb    = (const float*)d_in[20];
  const float* alog   = (const float*)d_in[21];
  const float* Dp     = (const float*)d_in[22];
  const float* opw    = (const float*)d_in[23];
  const float* lnw    = (const float*)d_in[24];
  const float* lnb    = (const float*)d_in[25];
  const float* nfw    = (const float*)d_in[26];
  const float* nfb    = (const float*)d_in[27];
  const float* n2w    = (const float*)d_in[28];
  const float* n2b    = (const float*)d_in[29];
  float* out = (float*)d_out;

  char* wsb = (char*)d_ws;
  size_t off = 0;
  auto alloc = [&](size_t bytes) -> void* {
    void* ptr = (void*)(wsb + off);
    off += ((bytes + 255) & ~(size_t)255);
    return ptr;
  };
  int*   vis   = (int*)alloc(NTOK * 4);
  int*   flag  = (int*)alloc(256);
  float* fg    = (float*)alloc((size_t)NTOK * NBK * 4);
  float* basep = (float*)alloc((size_t)NTOK * C1 * 4);
  float* h     = (float*)alloc((size_t)NTOK * DMODEL * 4);
  float* res   = (float*)alloc((size_t)NTOK * DMODEL * 4);
  float* hn    = (float*)alloc((size_t)NTOK * DMODEL * 4);
  float* mc    = (float*)alloc((size_t)NTOK * 3 * 4);
  float* t1    = (float*)alloc((size_t)NTOK * 128 * 4);
  short* c1lo  = (short*)alloc((size_t)C1 * NBK * 2);
  short* c1hi  = (short*)alloc((size_t)C1 * NBK * 2);
  short* c2wb  = (short*)alloc((size_t)DMODEL * F1K * 2);
  short* pw1b  = (short*)alloc((size_t)128 * 32 * 2);
  // overlap region: encoder chunk buffers vs mamba activations (disjoint in time)
  size_t regionBytes = (size_t)CHR * NBK * 2 + (size_t)CHR * F1K * 2;  // 22.8 MB
  char* region = (char*)alloc(regionBytes);
  short* nbg = (short*)region;
  short* f1  = (short*)(region + (size_t)CHR * NBK * 2);
  float* xz  = (float*)region;
  float* xic = (float*)(region + (size_t)NTOK * 1536 * 4);
  float* dbl = (float*)(region + (size_t)NTOK * (1536 + 768) * 4);
  float* ym  = (float*)(region + (size_t)NTOK * (1536 + 768 + 64) * 4);

  vis_kernel<<<1, 64, 0, stream>>>(maskp, vis, flag);
  mask_out_kernel<<<8, 256, 0, stream>>>(maskp, flag, out);

  // weight converts
  cvt_pad<<<(C1 * NBK + 255) / 256, 256, 0, stream>>>(c1w, C1, 0, c1lo, C1, FEAT, NBK);
  cvt_pad<<<(C1 * NBK + 255) / 256, 256, 0, stream>>>(c1w, C1, FEAT, c1hi, C1, FEAT, NBK);
  cvt_pad<<<(DMODEL * F1K + 255) / 256, 256, 0, stream>>>(c2w, C1, 0, c2wb, DMODEL, C1, F1K);
  cvt_pad<<<(128 * 32 + 255) / 256, 256, 0, stream>>>(pw1, 3, 0, pw1b, 128, 3, 32);

  GemmP z{};  // template with nulls
  // encoder: 2 chunks of 412 groups
  for (int c = 0; c < 2; ++c) {
    int g0 = c * CHG;
    gather_fg<<<CHG, 320, 0, stream>>>(nb, vis, g0, nbg, fg);
    {
      GemmP p = z;
      p.A = fg + (size_t)g0 * NBK; p.lda = NBK;
      p.Bbf = c1lo; p.ldb = NBK; p.bias = c1b;
      p.C = basep + (size_t)g0 * C1; p.ldc = C1;
      p.M = CHG; p.N = C1; p.K = NBK; p.Kp = NBK;
      gemm_mfma<EP_BIAS | EP_BBF16, 64><<<dim3(5, 7), 256, 0, stream>>>(p);
    }
    {
      GemmP p = z;
      p.Abf = nbg; p.lda = NBK;
      p.Bbf = c1hi; p.ldb = NBK;
      p.M = CHR; p.N = C1; p.K = NBK; p.Kp = NBK; p.g0 = g0;
      p.bng = bng; p.bnb = bnb; p.bnm = bnm; p.bnv = bnv;
      p.basep = basep; p.f1 = f1;
      gemm_mfma<EP_ENC1 | EP_ABF16 | EP_BBF16, 128><<<dim3(5, 103), 256, 0, stream>>>(p);
    }
    {
      GemmP p = z;
      p.Abf = f1; p.lda = F1K;
      p.Bbf = c2wb; p.ldb = F1K; p.bias = c2b;
      p.C = h; p.ldc = DMODEL;
      p.M = CHR; p.N = DMODEL; p.K = F1K; p.Kp = F1K; p.g0 = g0;
      gemm_mfma<EP_POOL | EP_ABF16 | EP_BBF16, 64><<<dim3(3, 206), 256, 0, stream>>>(p);
    }
  }

  // positional embedding accumulated into h
  gather_mc<<<(NTOK * 3 + 255) / 256, 256, 0, stream>>>(center, vis, mc);
  {
    GemmP p = z;
    p.A = mc; p.lda = 3;
    p.Bbf = pw1b; p.ldb = 32; p.bias = pb1;
    p.C = t1; p.ldc = 128;
    p.M = NTOK; p.N = 128; p.K = 3; p.Kp = 32;
    gemm_mfma<EP_BIAS | EP_GELU | EP_BBF16, 64><<<dim3(1, 13), 256, 0, stream>>>(p);
  }
  {
    GemmP p = z;
    p.A = t1; p.lda = 128;
    p.B = pw2; p.ldb = 128; p.bias = pb2;
    p.C = h; p.ldc = DMODEL;
    p.M = NTOK; p.N = DMODEL; p.K = 128; p.Kp = 128;
    gemm_mfma<EP_BIAS | EP_ACCUM, 64><<<dim3(3, 13), 256, 0, stream>>>(p);
  }

  for (int i = 0; i < 12; ++i) {
    ln4_kernel<<<(NTOK + 3) / 4, 256, 0, stream>>>(h, res, res, hn, lnw + i * DMODEL,
                                                   lnb + i * DMODEL, i > 0 ? 1 : 0);
    {
      GemmP p = z;
      p.A = hn; p.lda = DMODEL;
      p.B = ipw + (size_t)i * 2 * DIN * DMODEL; p.ldb = DMODEL;
      p.C = xz; p.ldc = 2 * DIN;
      p.M = NTOK; p.N = 2 * DIN; p.K = DMODEL; p.Kp = DMODEL;
      gemm_mfma<0, 64><<<dim3(12, 13), 256, 0, stream>>>(p);
    }
    {
      GemmP p = z;
      p.A = xz; p.lda = 2 * DIN;     // conv source
      p.B = xpw + (size_t)i * 56 * DIN; p.ldb = DIN;
      p.C = dbl; p.ldc = 56;
      p.M = NTOK; p.N = 56; p.K = DIN; p.Kp = DIN;
      p.cw = cw + (size_t)i * DIN * 4; p.cb = cb + (size_t)i * DIN; p.xic = xic;
      gemm_mfma<EP_CONV, 64><<<dim3(1, 13), 256, 0, stream>>>(p);
    }
    scan_fused<<<384, 256, 0, stream>>>(dbl, xic, xz, dpw + (size_t)i * DIN * 24,
                                        dpb + (size_t)i * DIN,
                                        alog + (size_t)i * DIN * 16,
                                        Dp + (size_t)i * DIN, ym);
    {
      GemmP p = z;
      p.A = ym; p.lda = DIN;
      p.B = opw + (size_t)i * DMODEL * DIN; p.ldb = DIN;
      p.C = h; p.ldc = DMODEL;
      p.M = NTOK; p.N = DMODEL; p.K = DIN; p.Kp = DIN;
      gemm_mfma<0, 64><<<dim3(3, 13), 256, 0, stream>>>(p);
    }
  }

  final_kernel<<<NTOK, 64, 0, stream>>>(h, res, nfw, nfb, n2w, n2b, out);
}

// Round 8
// 1906.130 us; speedup vs baseline: 2.7545x; 1.4316x over previous
//
#include <hip/hip_runtime.h>
#include <math.h>

#define GVIS 103
#define BB 8
#define GG 256
#define NPT 32
#define FEAT 273
#define C1 546
#define DMODEL 384
#define DIN 768
#define LSEQ 103
#define NTOK 824
#define EPSV 1e-5f
#define NBK 288          // padded K for point features (273->288)
#define F1K 576          // padded K for f1 (546->576)
#define CHG 412          // groups per encoder chunk
#define CHR (CHG * 32)   // rows per encoder chunk

typedef __attribute__((ext_vector_type(8))) short s16x8;
typedef __attribute__((ext_vector_type(4))) short s16x4;
typedef __attribute__((ext_vector_type(4))) float f32x4;

enum {
  EP_BIAS = 1, EP_GELU = 2, EP_ACCUM = 4, EP_ENC1 = 8, EP_POOL = 16,
  EP_ABF16 = 32, EP_BBF16 = 64
};

__device__ __forceinline__ short f2bf(float f) {
  unsigned u = __builtin_bit_cast(unsigned, f);
  u += 0x7fffu + ((u >> 16) & 1u);
  return (short)(u >> 16);
}

struct GemmP {
  const float* A; int lda;
  const short* Abf;
  const float* B; int ldb;
  const short* Bbf;
  const float* bias;
  float* C; int ldc;
  short* f1;
  int M, N, K, Kp, g0;
  const float* bng; const float* bnb; const float* bnm; const float* bnv;
  const float* basep;
};

// ---------------- MFMA GEMM: C[M,N] = A[M,K] * B[N,K]^T ----------------
// TM=128: 4 waves as 2x2 (64x64 each). TM=64: 4 waves as 1x4 (64x32 each).
template <int MODE, int TM>
__global__ __launch_bounds__(256) void gemm_mfma(GemmP p) {
  __shared__ short As[TM * 40];
  __shared__ short Bs[128 * 40];
  constexpr int WC = (TM == 128) ? 2 : 4;
  constexpr int NF = 128 / (WC * 16);
  const int t = threadIdx.x;
  const int m0 = blockIdx.y * TM, n0 = blockIdx.x * 128;
  const int srow = t >> 1, skh = (t & 1) * 16;
  const int lane = t & 63, wave = t >> 6;
  const int wr = wave / WC, wc = wave % WC;
  const int lrow = lane & 15, lk = (lane >> 4) * 8;

  const bool aRowIn = (TM == 128) ? true : (t < 128);
  const int arow = m0 + srow;
  const bool aValid = aRowIn && (arow < p.M);
  const bool bValid = (n0 + srow) < p.N;
  const float* aPtr = nullptr; const short* aPtrB = nullptr;
  if constexpr (MODE & EP_ABF16) { if (aValid) aPtrB = p.Abf + (size_t)arow * p.lda; }
  else { if (aValid) aPtr = p.A + (size_t)arow * p.lda; }
  const float* bPtrF = nullptr; const short* bPtrB = nullptr;
  if constexpr (MODE & EP_BBF16) { if (bValid) bPtrB = p.Bbf + (size_t)(n0 + srow) * p.ldb; }
  else { if (bValid) bPtrF = p.B + (size_t)(n0 + srow) * p.ldb; }
  const bool avec = ((p.lda & 3) == 0) && (p.K == p.Kp);
  const bool bvec = ((p.ldb & 3) == 0) && (p.K == p.Kp);

  f32x4 acc[4][NF];
#pragma unroll
  for (int i = 0; i < 4; ++i)
#pragma unroll
    for (int j = 0; j < NF; ++j) acc[i][j] = f32x4{0.f, 0.f, 0.f, 0.f};

  for (int k0 = 0; k0 < p.Kp; k0 += 32) {
    // ---- stage A ----
    if (aRowIn) {
      s16x8 q0 = {}, q1 = {};
      if (aValid) {
        if constexpr (MODE & EP_ABF16) {
          q0 = *(const s16x8*)(aPtrB + k0 + skh);
          q1 = *(const s16x8*)(aPtrB + k0 + skh + 8);
        } else {
          float v[16];
          if (avec) {
            f32x4 f0 = *(const f32x4*)(aPtr + k0 + skh);
            f32x4 f1v = *(const f32x4*)(aPtr + k0 + skh + 4);
            f32x4 f2v = *(const f32x4*)(aPtr + k0 + skh + 8);
            f32x4 f3v = *(const f32x4*)(aPtr + k0 + skh + 12);
#pragma unroll
            for (int j = 0; j < 4; ++j) {
              v[j] = f0[j]; v[j + 4] = f1v[j]; v[j + 8] = f2v[j]; v[j + 12] = f3v[j];
            }
          } else {
#pragma unroll
            for (int j = 0; j < 16; ++j) {
              int k = k0 + skh + j;
              v[j] = (k < p.K) ? aPtr[k] : 0.f;
            }
          }
#pragma unroll
          for (int j = 0; j < 8; ++j) { q0[j] = f2bf(v[j]); q1[j] = f2bf(v[j + 8]); }
        }
      }
      *(s16x8*)(As + srow * 40 + skh) = q0;
      *(s16x8*)(As + srow * 40 + skh + 8) = q1;
    }
    // ---- stage B ----
    {
      s16x8 q0 = {}, q1 = {};
      if (bValid) {
        if constexpr (MODE & EP_BBF16) {
          q0 = *(const s16x8*)(bPtrB + k0 + skh);
          q1 = *(const s16x8*)(bPtrB + k0 + skh + 8);
        } else {
          float v[16];
          if (bvec) {
            f32x4 f0 = *(const f32x4*)(bPtrF + k0 + skh);
            f32x4 f1v = *(const f32x4*)(bPtrF + k0 + skh + 4);
            f32x4 f2v = *(const f32x4*)(bPtrF + k0 + skh + 8);
            f32x4 f3v = *(const f32x4*)(bPtrF + k0 + skh + 12);
#pragma unroll
            for (int j = 0; j < 4; ++j) {
              v[j] = f0[j]; v[j + 4] = f1v[j]; v[j + 8] = f2v[j]; v[j + 12] = f3v[j];
            }
          } else {
#pragma unroll
            for (int j = 0; j < 16; ++j) {
              int k = k0 + skh + j;
              v[j] = (k < p.K) ? bPtrF[k] : 0.f;
            }
          }
#pragma unroll
          for (int j = 0; j < 8; ++j) { q0[j] = f2bf(v[j]); q1[j] = f2bf(v[j + 8]); }
        }
      }
      *(s16x8*)(Bs + srow * 40 + skh) = q0;
      *(s16x8*)(Bs + srow * 40 + skh + 8) = q1;
    }
    __syncthreads();
    s16x8 af[4], bfr[NF];
#pragma unroll
    for (int f = 0; f < 4; ++f)
      af[f] = *(const s16x8*)(As + (wr * 64 + f * 16 + lrow) * 40 + lk);
#pragma unroll
    for (int f = 0; f < NF; ++f)
      bfr[f] = *(const s16x8*)(Bs + (wc * (NF * 16) + f * 16 + lrow) * 40 + lk);
#pragma unroll
    for (int i = 0; i < 4; ++i)
#pragma unroll
      for (int j = 0; j < NF; ++j)
        acc[i][j] = __builtin_amdgcn_mfma_f32_16x16x32_bf16(af[i], bfr[j], acc[i][j], 0, 0, 0);
    __syncthreads();
  }

  // ---------------- epilogues ----------------
  if constexpr (MODE & EP_POOL) {
#pragma unroll
    for (int g2 = 0; g2 < 2; ++g2) {
#pragma unroll
      for (int fn = 0; fn < NF; ++fn) {
        float mx = -3.4e38f;
#pragma unroll
        for (int fm = 2 * g2; fm < 2 * g2 + 2; ++fm)
#pragma unroll
          for (int r = 0; r < 4; ++r) mx = fmaxf(mx, acc[fm][fn][r]);
        mx = fmaxf(mx, __shfl_xor(mx, 16));
        mx = fmaxf(mx, __shfl_xor(mx, 32));
        if ((lane >> 4) == 0) {
          int gi = p.g0 + ((m0 + wr * 64 + g2 * 32) >> 5);
          int o = n0 + wc * (NF * 16) + fn * 16 + lane;
          p.C[(size_t)gi * p.ldc + o] = mx + p.bias[o];
        }
      }
    }
  } else if constexpr (MODE & EP_ENC1) {
#pragma unroll
    for (int fm = 0; fm < 4; ++fm) {
      int mbase = m0 + wr * 64 + fm * 16 + (lane >> 4) * 4;
#pragma unroll
      for (int fn = 0; fn < NF; ++fn) {
        int o = n0 + wc * (NF * 16) + fn * 16 + lrow;
        if (o >= F1K) continue;
        if (o < C1) {
          float sc = p.bng[o] * rsqrtf(p.bnv[o] + EPSV);
          float sh = p.bnb[o] - p.bnm[o] * sc;
#pragma unroll
          for (int r = 0; r < 4; ++r) {
            int mm = mbase + r;
            int gi = p.g0 + (mm >> 5);
            float v = acc[fm][fn][r] + p.basep[(size_t)gi * C1 + o];
            p.f1[(size_t)mm * F1K + o] = f2bf(fmaxf(v * sc + sh, 0.f));
          }
        } else {
#pragma unroll
          for (int r = 0; r < 4; ++r) p.f1[(size_t)(mbase + r) * F1K + o] = 0;
        }
      }
    }
  } else {
#pragma unroll
    for (int fm = 0; fm < 4; ++fm) {
#pragma unroll
      for (int fn = 0; fn < NF; ++fn) {
        int o = n0 + wc * (NF * 16) + fn * 16 + lrow;
        if (o >= p.N) continue;
#pragma unroll
        for (int r = 0; r < 4; ++r) {
          int m = m0 + wr * 64 + fm * 16 + (lane >> 4) * 4 + r;
          if (m >= p.M) continue;
          float v = acc[fm][fn][r];
          if (MODE & EP_BIAS) v += p.bias[o];
          if (MODE & EP_GELU) v = 0.5f * v * (1.f + erff(v * 0.70710678118f));
          if (MODE & EP_ACCUM) v += p.C[(size_t)m * p.ldc + o];
          p.C[(size_t)m * p.ldc + o] = v;
        }
      }
    }
  }
}

// ---------------- weight convert/pad fp32 -> bf16 (padded rows) ----------------
__global__ void cvt_pad(const float* __restrict__ src, int srcld, int colOff,
                        short* __restrict__ dst, int nrows, int Kv, int Kp) {
  int idx = blockIdx.x * 256 + threadIdx.x;
  if (idx >= nrows * Kp) return;
  int r = idx / Kp, k = idx - r * Kp;
  dst[idx] = (k < Kv) ? f2bf(src[(size_t)r * srcld + colOff + k]) : (short)0;
}

// ---------------- contiguous vectorized fp32 -> bf16 ----------------
__global__ void cvt_vec4(const float* __restrict__ src, short* __restrict__ dst, int n4) {
  int i = blockIdx.x * 256 + threadIdx.x;
  if (i >= n4) return;
  f32x4 v = ((const f32x4*)src)[i];
  s16x4 o;
#pragma unroll
  for (int j = 0; j < 4; ++j) o[j] = f2bf(v[j]);
  ((s16x4*)dst)[i] = o;
}

// ---------------- vis list + mask dtype detection ----------------
__global__ void vis_kernel(const void* maskp, int* vis, int* flag) {
  __shared__ int isInt;
  if (threadIdx.x == 0) {
    const unsigned char* bp = (const unsigned char*)maskp;
    int s = 0;
    for (int i = 0; i < BB * GG; ++i) if (i & 3) s += bp[i];
    isInt = (s == 0) ? 1 : 0;
    flag[0] = isInt;
  }
  __syncthreads();
  int b = threadIdx.x;
  if (b < BB) {
    const int* ip = (const int*)maskp;
    const unsigned char* bp = (const unsigned char*)maskp;
    int cnt = 0;
    for (int g = 0; g < GG && cnt < GVIS; ++g) {
      int mv = isInt ? ip[b * GG + g] : (int)bp[b * GG + g];
      if (mv == 0) { vis[b * GVIS + cnt] = g; ++cnt; }
    }
    for (; cnt < GVIS; ++cnt) vis[b * GVIS + cnt] = 0;
  }
}

__global__ void mask_out_kernel(const void* maskp, const int* flag, float* out) {
  int i = blockIdx.x * 256 + threadIdx.x;
  if (i >= BB * GG) return;
  int mv = flag[0] ? ((const int*)maskp)[i] : (int)((const unsigned char*)maskp)[i];
  out[NTOK * DMODEL + i] = mv ? 1.f : 0.f;
}

// ---------------- gather visible groups -> compact bf16 + per-group max ----------------
__global__ __launch_bounds__(320) void gather_fg(const float* __restrict__ nb,
                                                 const int* __restrict__ vis, int g0,
                                                 short* __restrict__ nbg,
                                                 float* __restrict__ fg) {
  int gl = blockIdx.x;
  int gi = g0 + gl;
  int c = threadIdx.x;
  if (c >= NBK) return;
  int b = gi / GVIS;
  int g = vis[gi];
  size_t base = ((size_t)(b * GG + g)) * NPT * FEAT;
  size_t orow = (size_t)gl * 32;
  if (c < FEAT) {
    float mx = -3.4e38f;
#pragma unroll 4
    for (int r = 0; r < 32; ++r) {
      float v = nb[base + (size_t)r * FEAT + c];
      mx = fmaxf(mx, v);
      nbg[(orow + r) * NBK + c] = f2bf(v);
    }
    fg[(size_t)gi * NBK + c] = mx;
  } else {
    for (int r = 0; r < 32; ++r) nbg[(orow + r) * NBK + c] = 0;
    fg[(size_t)gi * NBK + c] = 0.f;
  }
}

// ---------------- center gather ----------------
__global__ void gather_mc(const float* __restrict__ center, const int* __restrict__ vis,
                          float* __restrict__ mc) {
  int i = blockIdx.x * 256 + threadIdx.x;
  if (i >= NTOK * 3) return;
  int tok = i / 3, c = i - tok * 3;
  int b = tok / GVIS;
  int g = vis[tok];
  mc[i] = center[((size_t)b * GG + g) * 3 + c];
}

// ---------------- layernorm: 4 tokens/block, bf16 output for GEMM A ----------------
__device__ __forceinline__ float wave_sum(float x) {
  for (int o = 32; o; o >>= 1) x += __shfl_xor(x, o);
  return x;
}

__global__ __launch_bounds__(256) void ln4_kernel(
    const float* __restrict__ h, const float* __restrict__ res_in,
    float* __restrict__ res_out, short* __restrict__ hnb,
    const float* __restrict__ w, const float* __restrict__ b, int add) {
  int tok = blockIdx.x * 4 + (threadIdx.x >> 6);
  int lane = threadIdx.x & 63;
  if (tok >= NTOK) return;
  const float* hr = h + (size_t)tok * DMODEL;
  float v[6];
#pragma unroll
  for (int j = 0; j < 6; ++j) {
    int c = lane + j * 64;
    float x = hr[c];
    if (add) x += res_in[(size_t)tok * DMODEL + c];
    v[j] = x;
  }
  float s = 0.f;
#pragma unroll
  for (int j = 0; j < 6; ++j) s += v[j];
  s = wave_sum(s);
  float mu = s * (1.f / DMODEL);
  float q = 0.f;
#pragma unroll
  for (int j = 0; j < 6; ++j) { float d = v[j] - mu; q += d * d; }
  q = wave_sum(q);
  float rstd = rsqrtf(q * (1.f / DMODEL) + EPSV);
#pragma unroll
  for (int j = 0; j < 6; ++j) {
    int c = lane + j * 64;
    res_out[(size_t)tok * DMODEL + c] = v[j];
    hnb[(size_t)tok * DMODEL + c] = f2bf((v[j] - mu) * rstd * w[c] + b[c]);
  }
}

__global__ __launch_bounds__(64) void final_kernel(
    const float* __restrict__ h, const float* __restrict__ res,
    const float* __restrict__ w1, const float* __restrict__ b1,
    const float* __restrict__ w2, const float* __restrict__ b2,
    float* __restrict__ out) {
  int tok = blockIdx.x, lane = threadIdx.x;
  float v[6];
#pragma unroll
  for (int j = 0; j < 6; ++j) {
    int c = lane + j * 64;
    v[j] = h[(size_t)tok * DMODEL + c] + res[(size_t)tok * DMODEL + c];
  }
  float s = 0.f;
#pragma unroll
  for (int j = 0; j < 6; ++j) s += v[j];
  s = wave_sum(s);
  float mu = s * (1.f / DMODEL);
  float q = 0.f;
#pragma unroll
  for (int j = 0; j < 6; ++j) { float d = v[j] - mu; q += d * d; }
  q = wave_sum(q);
  float rstd = rsqrtf(q * (1.f / DMODEL) + EPSV);
#pragma unroll
  for (int j = 0; j < 6; ++j) {
    int c = lane + j * 64;
    v[j] = (v[j] - mu) * rstd * w1[c] + b1[c];
  }
  s = 0.f;
#pragma unroll
  for (int j = 0; j < 6; ++j) s += v[j];
  s = wave_sum(s);
  mu = s * (1.f / DMODEL);
  q = 0.f;
#pragma unroll
  for (int j = 0; j < 6; ++j) { float d = v[j] - mu; q += d * d; }
  q = wave_sum(q);
  rstd = rsqrtf(q * (1.f / DMODEL) + EPSV);
#pragma unroll
  for (int j = 0; j < 6; ++j) {
    int c = lane + j * 64;
    out[(size_t)tok * DMODEL + c] = (v[j] - mu) * rstd * w2[c] + b2[c];
  }
}

// ---------------- causal depthwise conv (k=4) + silu, vectorized x4 ----------------
__global__ __launch_bounds__(256) void conv_silu(const float* __restrict__ xz,
                                                 const float* __restrict__ cw,
                                                 const float* __restrict__ cb,
                                                 float* __restrict__ xic,
                                                 short* __restrict__ xicb) {
  int idx = blockIdx.x * 256 + threadIdx.x;   // one thread = 4 channels of one token
  if (idx >= NTOK * (DIN / 4)) return;
  int tok = idx / (DIN / 4);
  int c4 = (idx - tok * (DIN / 4)) * 4;
  int b = tok / LSEQ, l = tok - b * LSEQ;
  f32x4 cwv[4];
#pragma unroll
  for (int j = 0; j < 4; ++j) cwv[j] = *(const f32x4*)(cw + (size_t)(c4 + j) * 4);
  f32x4 sv = *(const f32x4*)(cb + c4);
#pragma unroll
  for (int k = 0; k < 4; ++k) {
    int ls = l - 3 + k;
    if (ls < 0) continue;
    f32x4 xv = *(const f32x4*)(xz + (size_t)(b * LSEQ + ls) * (2 * DIN) + c4);
#pragma unroll
    for (int e = 0; e < 4; ++e) sv[e] = fmaf(cwv[e][k], xv[e], sv[e]);
  }
  s16x4 ob;
#pragma unroll
  for (int e = 0; e < 4; ++e) {
    sv[e] = sv[e] / (1.f + expf(-sv[e]));
    ob[e] = f2bf(sv[e]);
  }
  *(f32x4*)(xic + (size_t)tok * DIN + c4) = sv;
  *(s16x4*)(xicb + (size_t)tok * DIN + c4) = ob;
}

// ---------------- fused dt_proj + selective scan (LDS-resident), bf16 y out ----------------
__global__ __launch_bounds__(256) void scan_fused(
    const float* __restrict__ dbl, const float* __restrict__ xic,
    const float* __restrict__ xz, const float* __restrict__ dpw,
    const float* __restrict__ dpb, const float* __restrict__ alog,
    const float* __restrict__ Dp, short* __restrict__ ymb) {
  __shared__ float sdbl[LSEQ][56];
  __shared__ float sdt[LSEQ][16];
  __shared__ float sxi[LSEQ][16];
  __shared__ float sz[LSEQ][16];
  __shared__ short sy[LSEQ][16];
  int t = threadIdx.x;
  int b = blockIdx.x / 48, chunk = blockIdx.x % 48;
  int d0 = chunk * 16;
  for (int u = t; u < LSEQ * 56; u += 256) {
    int l = u / 56, cc = u - l * 56;
    sdbl[l][cc] = dbl[((size_t)b * LSEQ + l) * 56 + cc];
  }
  for (int u = t; u < LSEQ * 16; u += 256) {
    int l = u >> 4, dl = u & 15;
    sxi[l][dl] = xic[((size_t)b * LSEQ + l) * DIN + d0 + dl];
    sz[l][dl] = xz[((size_t)b * LSEQ + l) * (2 * DIN) + DIN + d0 + dl];
  }
  __syncthreads();
  for (int u = t; u < LSEQ * 16; u += 256) {
    int l = u >> 4, dl = u & 15;
    const float* wp = dpw + (size_t)(d0 + dl) * 24;
    float s = dpb[d0 + dl];
#pragma unroll
    for (int kk = 0; kk < 24; ++kk) s = fmaf(wp[kk], sdbl[l][kk], s);
    sdt[l][dl] = (s > 20.f) ? s : log1pf(expf(s));
  }
  __syncthreads();
  int s = t & 15, dloc = t >> 4;
  int d = d0 + dloc;
  float Av = -expf(alog[(size_t)d * 16 + s]);
  float Dv = Dp[d];
  float h = 0.f;
  for (int l = 0; l < LSEQ; ++l) {
    float dtv = sdt[l][dloc];
    float xiv = sxi[l][dloc];
    float hB = sdbl[l][24 + s], hC = sdbl[l][40 + s];
    h = fmaf(expf(dtv * Av), h, dtv * xiv * hB);
    float y = h * hC;
    y += __shfl_xor(y, 1);
    y += __shfl_xor(y, 2);
    y += __shfl_xor(y, 4);
    y += __shfl_xor(y, 8);
    if (s == 0) {
      float zv = sz[l][dloc];
      sy[l][dloc] = f2bf((y + xiv * Dv) * (zv / (1.f + expf(-zv))));
    }
  }
  __syncthreads();
  for (int u = t; u < LSEQ * 16; u += 256)
    ymb[((size_t)b * LSEQ + (u >> 4)) * DIN + d0 + (u & 15)] = sy[u >> 4][u & 15];
}

// ---------------- host launch ----------------
extern "C" void kernel_launch(void* const* d_in, const int* in_sizes, int n_in,
                              void* d_out, int out_size, void* d_ws, size_t ws_size,
                              hipStream_t stream) {
  const float* nb     = (const float*)d_in[0];
  const float* center = (const float*)d_in[1];
  const void*  maskp  = d_in[2];
  const float* c1w    = (const float*)d_in[3];
  const float* c1b    = (const float*)d_in[4];
  const float* bng    = (const float*)d_in[5];
  const float* bnb    = (const float*)d_in[6];
  const float* bnm    = (const float*)d_in[7];
  const float* bnv    = (const float*)d_in[8];
  const float* c2w    = (const float*)d_in[9];
  const float* c2b    = (const float*)d_in[10];
  const float* pw1    = (const float*)d_in[11];
  const float* pb1    = (const float*)d_in[12];
  const float* pw2    = (const float*)d_in[13];
  const float* pb2    = (const float*)d_in[14];
  const float* ipw    = (const float*)d_in[15];
  const float* cw     = (const float*)d_in[16];
  const float* cb     = (const float*)d_in[17];
  const float* xpw    = (const float*)d_in[18];
  const float* dpw    = (const float*)d_in[19];
  const float* dpb    = (const float*)d_in[20];
  const float* alog   = (const float*)d_in[21];
  const float* Dp     = (const float*)d_in[22];
  const float* opw    = (const float*)d_in[23];
  const float* lnw    = (const float*)d_in[24];
  const float* lnb    = (const float*)d_in[25];
  const float* nfw    = (const float*)d_in[26];
  const float* nfb    = (const float*)d_in[27];
  const float* n2w    = (const float*)d_in[28];
  const float* n2b    = (const float*)d_in[29];
  float* out = (float*)d_out;

  char* wsb = (char*)d_ws;
  size_t off = 0;
  auto alloc = [&](size_t bytes) -> void* {
    void* ptr = (void*)(wsb + off);
    off += ((bytes + 255) & ~(size_t)255);
    return ptr;
  };
  int*   vis   = (int*)alloc(NTOK * 4);
  int*   flag  = (int*)alloc(256);
  float* fg    = (float*)alloc((size_t)NTOK * NBK * 4);
  float* basep = (float*)alloc((size_t)NTOK * C1 * 4);
  float* h     = (float*)alloc((size_t)NTOK * DMODEL * 4);
  float* res   = (float*)alloc((size_t)NTOK * DMODEL * 4);
  float* mc    = (float*)alloc((size_t)NTOK * 3 * 4);
  float* t1    = (float*)alloc((size_t)NTOK * 128 * 4);
  short* c1lo  = (short*)alloc((size_t)C1 * NBK * 2);
  short* c1hi  = (short*)alloc((size_t)C1 * NBK * 2);
  short* c2wb  = (short*)alloc((size_t)DMODEL * F1K * 2);
  short* pw1b  = (short*)alloc((size_t)128 * 32 * 2);
  // overlap region: encoder chunk buffers vs mamba activations (disjoint in time)
  size_t regionBytes = (size_t)CHR * NBK * 2 + (size_t)CHR * F1K * 2;  // 22.8 MB
  char* region = (char*)alloc(regionBytes);
  // encoder phase
  short* nbg = (short*)region;
  short* f1  = (short*)(region + (size_t)CHR * NBK * 2);
  // mamba phase (all within region; high-water ~12 MB < 22.8 MB)
  size_t roff = 0;
  auto ralloc = [&](size_t bytes) -> void* {
    void* ptr = (void*)(region + roff);
    roff += ((bytes + 255) & ~(size_t)255);
    return ptr;
  };
  float* xz   = (float*)ralloc((size_t)NTOK * 1536 * 4);
  float* xic  = (float*)ralloc((size_t)NTOK * DIN * 4);
  float* dbl  = (float*)ralloc((size_t)NTOK * 64 * 4);
  short* xicb = (short*)ralloc((size_t)NTOK * DIN * 2);
  short* hnb  = (short*)ralloc((size_t)NTOK * DMODEL * 2);
  short* ymb  = (short*)ralloc((size_t)NTOK * DIN * 2);
  short* xpwb = (short*)ralloc((size_t)12 * 56 * DIN * 2);

  vis_kernel<<<1, 64, 0, stream>>>(maskp, vis, flag);
  mask_out_kernel<<<8, 256, 0, stream>>>(maskp, flag, out);

  // encoder weight converts
  cvt_pad<<<(C1 * NBK + 255) / 256, 256, 0, stream>>>(c1w, C1, 0, c1lo, C1, FEAT, NBK);
  cvt_pad<<<(C1 * NBK + 255) / 256, 256, 0, stream>>>(c1w, C1, FEAT, c1hi, C1, FEAT, NBK);
  cvt_pad<<<(DMODEL * F1K + 255) / 256, 256, 0, stream>>>(c2w, C1, 0, c2wb, DMODEL, C1, F1K);
  cvt_pad<<<(128 * 32 + 255) / 256, 256, 0, stream>>>(pw1, 3, 0, pw1b, 128, 3, 32);

  GemmP z{};
  // encoder: 2 chunks of 412 groups
  for (int c = 0; c < 2; ++c) {
    int g0 = c * CHG;
    gather_fg<<<CHG, 320, 0, stream>>>(nb, vis, g0, nbg, fg);
    {
      GemmP p = z;
      p.A = fg + (size_t)g0 * NBK; p.lda = NBK;
      p.Bbf = c1lo; p.ldb = NBK; p.bias = c1b;
      p.C = basep + (size_t)g0 * C1; p.ldc = C1;
      p.M = CHG; p.N = C1; p.K = NBK; p.Kp = NBK;
      gemm_mfma<EP_BIAS | EP_BBF16, 64><<<dim3(5, 7), 256, 0, stream>>>(p);
    }
    {
      GemmP p = z;
      p.Abf = nbg; p.lda = NBK;
      p.Bbf = c1hi; p.ldb = NBK;
      p.M = CHR; p.N = C1; p.K = NBK; p.Kp = NBK; p.g0 = g0;
      p.bng = bng; p.bnb = bnb; p.bnm = bnm; p.bnv = bnv;
      p.basep = basep; p.f1 = f1;
      gemm_mfma<EP_ENC1 | EP_ABF16 | EP_BBF16, 128><<<dim3(5, 103), 256, 0, stream>>>(p);
    }
    {
      GemmP p = z;
      p.Abf = f1; p.lda = F1K;
      p.Bbf = c2wb; p.ldb = F1K; p.bias = c2b;
      p.C = h; p.ldc = DMODEL;
      p.M = CHR; p.N = DMODEL; p.K = F1K; p.Kp = F1K; p.g0 = g0;
      gemm_mfma<EP_POOL | EP_ABF16 | EP_BBF16, 64><<<dim3(3, 206), 256, 0, stream>>>(p);
    }
  }

  // positional embedding accumulated into h
  gather_mc<<<(NTOK * 3 + 255) / 256, 256, 0, stream>>>(center, vis, mc);
  {
    GemmP p = z;
    p.A = mc; p.lda = 3;
    p.Bbf = pw1b; p.ldb = 32; p.bias = pb1;
    p.C = t1; p.ldc = 128;
    p.M = NTOK; p.N = 128; p.K = 3; p.Kp = 32;
    gemm_mfma<EP_BIAS | EP_GELU | EP_BBF16, 64><<<dim3(1, 13), 256, 0, stream>>>(p);
  }
  {
    GemmP p = z;
    p.A = t1; p.lda = 128;
    p.B = pw2; p.ldb = 128; p.bias = pb2;
    p.C = h; p.ldc = DMODEL;
    p.M = NTOK; p.N = DMODEL; p.K = 128; p.Kp = 128;
    gemm_mfma<EP_BIAS | EP_ACCUM, 64><<<dim3(3, 13), 256, 0, stream>>>(p);
  }

  // x_proj weights -> bf16 (after encoder: region reuse is now safe)
  cvt_vec4<<<(12 * 56 * DIN / 4 + 255) / 256, 256, 0, stream>>>(xpw, xpwb, 12 * 56 * DIN / 4);

  for (int i = 0; i < 12; ++i) {
    ln4_kernel<<<(NTOK + 3) / 4, 256, 0, stream>>>(h, res, res, hnb, lnw + i * DMODEL,
                                                   lnb + i * DMODEL, i > 0 ? 1 : 0);
    {
      GemmP p = z;
      p.Abf = hnb; p.lda = DMODEL;
      p.B = ipw + (size_t)i * 2 * DIN * DMODEL; p.ldb = DMODEL;
      p.C = xz; p.ldc = 2 * DIN;
      p.M = NTOK; p.N = 2 * DIN; p.K = DMODEL; p.Kp = DMODEL;
      gemm_mfma<EP_ABF16, 64><<<dim3(12, 13), 256, 0, stream>>>(p);
    }
    conv_silu<<<(NTOK * (DIN / 4) + 255) / 256, 256, 0, stream>>>(
        xz, cw + (size_t)i * DIN * 4, cb + (size_t)i * DIN, xic, xicb);
    {
      GemmP p = z;
      p.Abf = xicb; p.lda = DIN;
      p.Bbf = xpwb + (size_t)i * 56 * DIN; p.ldb = DIN;
      p.C = dbl; p.ldc = 56;
      p.M = NTOK; p.N = 56; p.K = DIN; p.Kp = DIN;
      gemm_mfma<EP_ABF16 | EP_BBF16, 64><<<dim3(1, 13), 256, 0, stream>>>(p);
    }
    scan_fused<<<384, 256, 0, stream>>>(dbl, xic, xz, dpw + (size_t)i * DIN * 24,
                                        dpb + (size_t)i * DIN,
                                        alog + (size_t)i * DIN * 16,
                                        Dp + (size_t)i * DIN, ymb);
    {
      GemmP p = z;
      p.Abf = ymb; p.lda = DIN;
      p.B = opw + (size_t)i * DMODEL * DIN; p.ldb = DIN;
      p.C = h; p.ldc = DMODEL;
      p.M = NTOK; p.N = DMODEL; p.K = DIN; p.Kp = DIN;
      gemm_mfma<EP_ABF16, 64><<<dim3(3, 13), 256, 0, stream>>>(p);
    }
  }

  final_kernel<<<NTOK, 64, 0, stream>>>(h, res, nfw, nfb, n2w, n2b, out);
}

// Round 9
// 1672.053 us; speedup vs baseline: 3.1401x; 1.1400x over previous
//
#include <hip/hip_runtime.h>
#include <math.h>

#define GVIS 103
#define BB 8
#define GG 256
#define NPT 32
#define FEAT 273
#define C1 546
#define DMODEL 384
#define DIN 768
#define LSEQ 103
#define NTOK 824
#define EPSV 1e-5f
#define NBK 288          // padded K for point features (273->288)
#define F1K 576          // padded K for f1 (546->576)
#define CHG 412          // groups per encoder chunk
#define CHR (CHG * 32)   // rows per encoder chunk

typedef __attribute__((ext_vector_type(8))) short s16x8;
typedef __attribute__((ext_vector_type(4))) short s16x4;
typedef __attribute__((ext_vector_type(4))) float f32x4;

enum {
  EP_BIAS = 1, EP_GELU = 2, EP_ACCUM = 4, EP_ENC1 = 8, EP_POOL = 16,
  EP_ABF16 = 32, EP_BBF16 = 64
};

__device__ __forceinline__ short f2bf(float f) {
  unsigned u = __builtin_bit_cast(unsigned, f);
  u += 0x7fffu + ((u >> 16) & 1u);
  return (short)(u >> 16);
}

struct GemmP {
  const float* A; int lda;
  const short* Abf;
  const float* B; int ldb;
  const short* Bbf;
  const float* bias;
  float* C; int ldc;
  short* f1;
  int M, N, K, Kp, g0;
  const float* bng; const float* bnb; const float* bnm; const float* bnv;
  const float* basep;
};

// ---------------- MFMA GEMM: C[M,N] = A[M,K] * B[N,K]^T ----------------
// TM=128: 4 waves as 2x2 (64x64 each). TM=64: 4 waves as 1x4 (64x32 each).
template <int MODE, int TM>
__global__ __launch_bounds__(256) void gemm_mfma(GemmP p) {
  __shared__ short As[TM * 40];
  __shared__ short Bs[128 * 40];
  constexpr int WC = (TM == 128) ? 2 : 4;
  constexpr int NF = 128 / (WC * 16);
  const int t = threadIdx.x;
  const int m0 = blockIdx.y * TM, n0 = blockIdx.x * 128;
  const int srow = t >> 1, skh = (t & 1) * 16;
  const int lane = t & 63, wave = t >> 6;
  const int wr = wave / WC, wc = wave % WC;
  const int lrow = lane & 15, lk = (lane >> 4) * 8;

  const bool aRowIn = (TM == 128) ? true : (t < 128);
  const int arow = m0 + srow;
  const bool aValid = aRowIn && (arow < p.M);
  const bool bValid = (n0 + srow) < p.N;
  const float* aPtr = nullptr; const short* aPtrB = nullptr;
  if constexpr (MODE & EP_ABF16) { if (aValid) aPtrB = p.Abf + (size_t)arow * p.lda; }
  else { if (aValid) aPtr = p.A + (size_t)arow * p.lda; }
  const float* bPtrF = nullptr; const short* bPtrB = nullptr;
  if constexpr (MODE & EP_BBF16) { if (bValid) bPtrB = p.Bbf + (size_t)(n0 + srow) * p.ldb; }
  else { if (bValid) bPtrF = p.B + (size_t)(n0 + srow) * p.ldb; }
  const bool avec = ((p.lda & 3) == 0) && (p.K == p.Kp);
  const bool bvec = ((p.ldb & 3) == 0) && (p.K == p.Kp);

  f32x4 acc[4][NF];
#pragma unroll
  for (int i = 0; i < 4; ++i)
#pragma unroll
    for (int j = 0; j < NF; ++j) acc[i][j] = f32x4{0.f, 0.f, 0.f, 0.f};

  for (int k0 = 0; k0 < p.Kp; k0 += 32) {
    // ---- stage A ----
    if (aRowIn) {
      s16x8 q0 = {}, q1 = {};
      if (aValid) {
        if constexpr (MODE & EP_ABF16) {
          q0 = *(const s16x8*)(aPtrB + k0 + skh);
          q1 = *(const s16x8*)(aPtrB + k0 + skh + 8);
        } else {
          float v[16];
          if (avec) {
            f32x4 f0 = *(const f32x4*)(aPtr + k0 + skh);
            f32x4 f1v = *(const f32x4*)(aPtr + k0 + skh + 4);
            f32x4 f2v = *(const f32x4*)(aPtr + k0 + skh + 8);
            f32x4 f3v = *(const f32x4*)(aPtr + k0 + skh + 12);
#pragma unroll
            for (int j = 0; j < 4; ++j) {
              v[j] = f0[j]; v[j + 4] = f1v[j]; v[j + 8] = f2v[j]; v[j + 12] = f3v[j];
            }
          } else {
#pragma unroll
            for (int j = 0; j < 16; ++j) {
              int k = k0 + skh + j;
              v[j] = (k < p.K) ? aPtr[k] : 0.f;
            }
          }
#pragma unroll
          for (int j = 0; j < 8; ++j) { q0[j] = f2bf(v[j]); q1[j] = f2bf(v[j + 8]); }
        }
      }
      *(s16x8*)(As + srow * 40 + skh) = q0;
      *(s16x8*)(As + srow * 40 + skh + 8) = q1;
    }
    // ---- stage B ----
    {
      s16x8 q0 = {}, q1 = {};
      if (bValid) {
        if constexpr (MODE & EP_BBF16) {
          q0 = *(const s16x8*)(bPtrB + k0 + skh);
          q1 = *(const s16x8*)(bPtrB + k0 + skh + 8);
        } else {
          float v[16];
          if (bvec) {
            f32x4 f0 = *(const f32x4*)(bPtrF + k0 + skh);
            f32x4 f1v = *(const f32x4*)(bPtrF + k0 + skh + 4);
            f32x4 f2v = *(const f32x4*)(bPtrF + k0 + skh + 8);
            f32x4 f3v = *(const f32x4*)(bPtrF + k0 + skh + 12);
#pragma unroll
            for (int j = 0; j < 4; ++j) {
              v[j] = f0[j]; v[j + 4] = f1v[j]; v[j + 8] = f2v[j]; v[j + 12] = f3v[j];
            }
          } else {
#pragma unroll
            for (int j = 0; j < 16; ++j) {
              int k = k0 + skh + j;
              v[j] = (k < p.K) ? bPtrF[k] : 0.f;
            }
          }
#pragma unroll
          for (int j = 0; j < 8; ++j) { q0[j] = f2bf(v[j]); q1[j] = f2bf(v[j + 8]); }
        }
      }
      *(s16x8*)(Bs + srow * 40 + skh) = q0;
      *(s16x8*)(Bs + srow * 40 + skh + 8) = q1;
    }
    __syncthreads();
    s16x8 af[4], bfr[NF];
#pragma unroll
    for (int f = 0; f < 4; ++f)
      af[f] = *(const s16x8*)(As + (wr * 64 + f * 16 + lrow) * 40 + lk);
#pragma unroll
    for (int f = 0; f < NF; ++f)
      bfr[f] = *(const s16x8*)(Bs + (wc * (NF * 16) + f * 16 + lrow) * 40 + lk);
#pragma unroll
    for (int i = 0; i < 4; ++i)
#pragma unroll
      for (int j = 0; j < NF; ++j)
        acc[i][j] = __builtin_amdgcn_mfma_f32_16x16x32_bf16(af[i], bfr[j], acc[i][j], 0, 0, 0);
    __syncthreads();
  }

  // ---------------- epilogues ----------------
  if constexpr (MODE & EP_POOL) {
#pragma unroll
    for (int g2 = 0; g2 < 2; ++g2) {
#pragma unroll
      for (int fn = 0; fn < NF; ++fn) {
        float mx = -3.4e38f;
#pragma unroll
        for (int fm = 2 * g2; fm < 2 * g2 + 2; ++fm)
#pragma unroll
          for (int r = 0; r < 4; ++r) mx = fmaxf(mx, acc[fm][fn][r]);
        mx = fmaxf(mx, __shfl_xor(mx, 16));
        mx = fmaxf(mx, __shfl_xor(mx, 32));
        if ((lane >> 4) == 0) {
          int gi = p.g0 + ((m0 + wr * 64 + g2 * 32) >> 5);
          int o = n0 + wc * (NF * 16) + fn * 16 + lane;
          p.C[(size_t)gi * p.ldc + o] = mx + p.bias[o];
        }
      }
    }
  } else if constexpr (MODE & EP_ENC1) {
#pragma unroll
    for (int fm = 0; fm < 4; ++fm) {
      int mbase = m0 + wr * 64 + fm * 16 + (lane >> 4) * 4;
#pragma unroll
      for (int fn = 0; fn < NF; ++fn) {
        int o = n0 + wc * (NF * 16) + fn * 16 + lrow;
        if (o >= F1K) continue;
        if (o < C1) {
          float sc = p.bng[o] * rsqrtf(p.bnv[o] + EPSV);
          float sh = p.bnb[o] - p.bnm[o] * sc;
#pragma unroll
          for (int r = 0; r < 4; ++r) {
            int mm = mbase + r;
            int gi = p.g0 + (mm >> 5);
            float v = acc[fm][fn][r] + p.basep[(size_t)gi * C1 + o];
            p.f1[(size_t)mm * F1K + o] = f2bf(fmaxf(v * sc + sh, 0.f));
          }
        } else {
#pragma unroll
          for (int r = 0; r < 4; ++r) p.f1[(size_t)(mbase + r) * F1K + o] = 0;
        }
      }
    }
  } else {
#pragma unroll
    for (int fm = 0; fm < 4; ++fm) {
#pragma unroll
      for (int fn = 0; fn < NF; ++fn) {
        int o = n0 + wc * (NF * 16) + fn * 16 + lrow;
        if (o >= p.N) continue;
#pragma unroll
        for (int r = 0; r < 4; ++r) {
          int m = m0 + wr * 64 + fm * 16 + (lane >> 4) * 4 + r;
          if (m >= p.M) continue;
          float v = acc[fm][fn][r];
          if (MODE & EP_BIAS) v += p.bias[o];
          if (MODE & EP_GELU) v = 0.5f * v * (1.f + erff(v * 0.70710678118f));
          if (MODE & EP_ACCUM) v += p.C[(size_t)m * p.ldc + o];
          p.C[(size_t)m * p.ldc + o] = v;
        }
      }
    }
  }
}

// ---------------- weight convert/pad fp32 -> bf16 (padded rows) ----------------
__global__ void cvt_pad(const float* __restrict__ src, int srcld, int colOff,
                        short* __restrict__ dst, int nrows, int Kv, int Kp) {
  int idx = blockIdx.x * 256 + threadIdx.x;
  if (idx >= nrows * Kp) return;
  int r = idx / Kp, k = idx - r * Kp;
  dst[idx] = (k < Kv) ? f2bf(src[(size_t)r * srcld + colOff + k]) : (short)0;
}

// ---------------- contiguous vectorized fp32 -> bf16 ----------------
__global__ void cvt_vec4(const float* __restrict__ src, short* __restrict__ dst, int n4) {
  int i = blockIdx.x * 256 + threadIdx.x;
  if (i >= n4) return;
  f32x4 v = ((const f32x4*)src)[i];
  s16x4 o;
#pragma unroll
  for (int j = 0; j < 4; ++j) o[j] = f2bf(v[j]);
  ((s16x4*)dst)[i] = o;
}

// ---------------- parallel vis list + mask dtype detect + mask echo ----------------
__global__ __launch_bounds__(512) void vis_kernel2(const void* maskp, int* vis,
                                                   float* out) {
  __shared__ int red[8];
  __shared__ int isIntSh;
  int t = threadIdx.x;
  const unsigned char* bp = (const unsigned char*)maskp;
  const int* ip = (const int*)maskp;
  // dtype detect: int32 iff all bytes at (i&3)!=0 are zero
  int s = 0;
  for (int i = t; i < BB * GG; i += 512) if (i & 3) s += bp[i];
  for (int o = 32; o; o >>= 1) s += __shfl_xor(s, o);
  if ((t & 63) == 0) red[t >> 6] = s;
  __syncthreads();
  if (t == 0) {
    int tot = 0;
    for (int w = 0; w < 8; ++w) tot += red[w];
    isIntSh = (tot == 0) ? 1 : 0;
  }
  __syncthreads();
  int isInt = isIntSh;
  // mask echo into output tail
  for (int i = t; i < BB * GG; i += 512) {
    int mv = isInt ? ip[i] : (int)bp[i];
    out[NTOK * DMODEL + i] = mv ? 1.f : 0.f;
  }
  // visible-list: wave w = batch w; lane owns 4 contiguous groups
  int w = t >> 6, lane = t & 63;
  int cnt = 0;
  int gs[4];
#pragma unroll
  for (int j = 0; j < 4; ++j) {
    int g = lane * 4 + j;
    int mv = isInt ? ip[w * GG + g] : (int)bp[w * GG + g];
    if (!mv) gs[cnt++] = g;
  }
  int inc = cnt;
  for (int o = 1; o < 64; o <<= 1) {
    int v = __shfl_up(inc, o);
    if (lane >= o) inc += v;
  }
  int base = inc - cnt;
  for (int j = 0; j < cnt; ++j) {
    int pos = base + j;
    if (pos < GVIS) vis[w * GVIS + pos] = gs[j];
  }
  int total = __shfl(inc, 63);
  for (int pos = total + lane; pos < GVIS; pos += 64) vis[w * GVIS + pos] = 0;
}

// ---------------- gather visible groups -> compact bf16 + per-group max ----------------
__global__ __launch_bounds__(320) void gather_fg(const float* __restrict__ nb,
                                                 const int* __restrict__ vis, int g0,
                                                 short* __restrict__ nbg,
                                                 float* __restrict__ fg) {
  int gl = blockIdx.x;
  int gi = g0 + gl;
  int c = threadIdx.x;
  if (c >= NBK) return;
  int b = gi / GVIS;
  int g = vis[gi];
  size_t base = ((size_t)(b * GG + g)) * NPT * FEAT;
  size_t orow = (size_t)gl * 32;
  if (c < FEAT) {
    float mx = -3.4e38f;
#pragma unroll 4
    for (int r = 0; r < 32; ++r) {
      float v = nb[base + (size_t)r * FEAT + c];
      mx = fmaxf(mx, v);
      nbg[(orow + r) * NBK + c] = f2bf(v);
    }
    fg[(size_t)gi * NBK + c] = mx;
  } else {
    for (int r = 0; r < 32; ++r) nbg[(orow + r) * NBK + c] = 0;
    fg[(size_t)gi * NBK + c] = 0.f;
  }
}

// ---------------- center gather ----------------
__global__ void gather_mc(const float* __restrict__ center, const int* __restrict__ vis,
                          float* __restrict__ mc) {
  int i = blockIdx.x * 256 + threadIdx.x;
  if (i >= NTOK * 3) return;
  int tok = i / 3, c = i - tok * 3;
  int b = tok / GVIS;
  int g = vis[tok];
  mc[i] = center[((size_t)b * GG + g) * 3 + c];
}

// ---------------- layernorm: 4 tokens/block, bf16 output for GEMM A ----------------
__device__ __forceinline__ float wave_sum(float x) {
  for (int o = 32; o; o >>= 1) x += __shfl_xor(x, o);
  return x;
}

__global__ __launch_bounds__(256) void ln4_kernel(
    const float* __restrict__ h, const float* __restrict__ res_in,
    float* __restrict__ res_out, short* __restrict__ hnb,
    const float* __restrict__ w, const float* __restrict__ b, int add) {
  int tok = blockIdx.x * 4 + (threadIdx.x >> 6);
  int lane = threadIdx.x & 63;
  if (tok >= NTOK) return;
  const float* hr = h + (size_t)tok * DMODEL;
  float v[6];
#pragma unroll
  for (int j = 0; j < 6; ++j) {
    int c = lane + j * 64;
    float x = hr[c];
    if (add) x += res_in[(size_t)tok * DMODEL + c];
    v[j] = x;
  }
  float s = 0.f;
#pragma unroll
  for (int j = 0; j < 6; ++j) s += v[j];
  s = wave_sum(s);
  float mu = s * (1.f / DMODEL);
  float q = 0.f;
#pragma unroll
  for (int j = 0; j < 6; ++j) { float d = v[j] - mu; q += d * d; }
  q = wave_sum(q);
  float rstd = rsqrtf(q * (1.f / DMODEL) + EPSV);
#pragma unroll
  for (int j = 0; j < 6; ++j) {
    int c = lane + j * 64;
    res_out[(size_t)tok * DMODEL + c] = v[j];
    hnb[(size_t)tok * DMODEL + c] = f2bf((v[j] - mu) * rstd * w[c] + b[c]);
  }
}

__global__ __launch_bounds__(64) void final_kernel(
    const float* __restrict__ h, const float* __restrict__ res,
    const float* __restrict__ w1, const float* __restrict__ b1,
    const float* __restrict__ w2, const float* __restrict__ b2,
    float* __restrict__ out) {
  int tok = blockIdx.x, lane = threadIdx.x;
  float v[6];
#pragma unroll
  for (int j = 0; j < 6; ++j) {
    int c = lane + j * 64;
    v[j] = h[(size_t)tok * DMODEL + c] + res[(size_t)tok * DMODEL + c];
  }
  float s = 0.f;
#pragma unroll
  for (int j = 0; j < 6; ++j) s += v[j];
  s = wave_sum(s);
  float mu = s * (1.f / DMODEL);
  float q = 0.f;
#pragma unroll
  for (int j = 0; j < 6; ++j) { float d = v[j] - mu; q += d * d; }
  q = wave_sum(q);
  float rstd = rsqrtf(q * (1.f / DMODEL) + EPSV);
#pragma unroll
  for (int j = 0; j < 6; ++j) {
    int c = lane + j * 64;
    v[j] = (v[j] - mu) * rstd * w1[c] + b1[c];
  }
  s = 0.f;
#pragma unroll
  for (int j = 0; j < 6; ++j) s += v[j];
  s = wave_sum(s);
  mu = s * (1.f / DMODEL);
  q = 0.f;
#pragma unroll
  for (int j = 0; j < 6; ++j) { float d = v[j] - mu; q += d * d; }
  q = wave_sum(q);
  rstd = rsqrtf(q * (1.f / DMODEL) + EPSV);
#pragma unroll
  for (int j = 0; j < 6; ++j) {
    int c = lane + j * 64;
    out[(size_t)tok * DMODEL + c] = (v[j] - mu) * rstd * w2[c] + b2[c];
  }
}

// ---------------- causal depthwise conv (k=4) + silu, vectorized x4 ----------------
__global__ __launch_bounds__(256) void conv_silu(const float* __restrict__ xz,
                                                 const float* __restrict__ cw,
                                                 const float* __restrict__ cb,
                                                 float* __restrict__ xic,
                                                 short* __restrict__ xicb) {
  int idx = blockIdx.x * 256 + threadIdx.x;   // one thread = 4 channels of one token
  if (idx >= NTOK * (DIN / 4)) return;
  int tok = idx / (DIN / 4);
  int c4 = (idx - tok * (DIN / 4)) * 4;
  int b = tok / LSEQ, l = tok - b * LSEQ;
  f32x4 cwv[4];
#pragma unroll
  for (int j = 0; j < 4; ++j) cwv[j] = *(const f32x4*)(cw + (size_t)(c4 + j) * 4);
  f32x4 sv = *(const f32x4*)(cb + c4);
#pragma unroll
  for (int k = 0; k < 4; ++k) {
    int ls = l - 3 + k;
    if (ls < 0) continue;
    f32x4 xv = *(const f32x4*)(xz + (size_t)(b * LSEQ + ls) * (2 * DIN) + c4);
#pragma unroll
    for (int e = 0; e < 4; ++e) sv[e] = fmaf(cwv[e][k], xv[e], sv[e]);
  }
  s16x4 ob;
#pragma unroll
  for (int e = 0; e < 4; ++e) {
    sv[e] = sv[e] / (1.f + expf(-sv[e]));
    ob[e] = f2bf(sv[e]);
  }
  *(f32x4*)(xic + (size_t)tok * DIN + c4) = sv;
  *(s16x4*)(xicb + (size_t)tok * DIN + c4) = ob;
}

// ---------------- fused dt_proj + selective scan (LDS-resident), bf16 y out ----------------
__global__ __launch_bounds__(256) void scan_fused(
    const float* __restrict__ dbl, const float* __restrict__ xic,
    const float* __restrict__ xz, const float* __restrict__ dpw,
    const float* __restrict__ dpb, const float* __restrict__ alog,
    const float* __restrict__ Dp, short* __restrict__ ymb) {
  __shared__ float sdbl[LSEQ][56];
  __shared__ float sdt[LSEQ][16];
  __shared__ float sxi[LSEQ][16];
  __shared__ float sz[LSEQ][16];
  __shared__ short sy[LSEQ][16];
  int t = threadIdx.x;
  int b = blockIdx.x / 48, chunk = blockIdx.x % 48;
  int d0 = chunk * 16;
  for (int u = t; u < LSEQ * 56; u += 256) {
    int l = u / 56, cc = u - l * 56;
    sdbl[l][cc] = dbl[((size_t)b * LSEQ + l) * 56 + cc];
  }
  for (int u = t; u < LSEQ * 16; u += 256) {
    int l = u >> 4, dl = u & 15;
    sxi[l][dl] = xic[((size_t)b * LSEQ + l) * DIN + d0 + dl];
    sz[l][dl] = xz[((size_t)b * LSEQ + l) * (2 * DIN) + DIN + d0 + dl];
  }
  __syncthreads();
  for (int u = t; u < LSEQ * 16; u += 256) {
    int l = u >> 4, dl = u & 15;
    const float* wp = dpw + (size_t)(d0 + dl) * 24;
    float s = dpb[d0 + dl];
#pragma unroll
    for (int kk = 0; kk < 24; ++kk) s = fmaf(wp[kk], sdbl[l][kk], s);
    sdt[l][dl] = (s > 20.f) ? s : log1pf(expf(s));
  }
  __syncthreads();
  int s = t & 15, dloc = t >> 4;
  int d = d0 + dloc;
  float Av = -expf(alog[(size_t)d * 16 + s]);
  float Dv = Dp[d];
  float h = 0.f;
  for (int l = 0; l < LSEQ; ++l) {
    float dtv = sdt[l][dloc];
    float xiv = sxi[l][dloc];
    float hB = sdbl[l][24 + s], hC = sdbl[l][40 + s];
    h = fmaf(expf(dtv * Av), h, dtv * xiv * hB);
    float y = h * hC;
    y += __shfl_xor(y, 1);
    y += __shfl_xor(y, 2);
    y += __shfl_xor(y, 4);
    y += __shfl_xor(y, 8);
    if (s == 0) {
      float zv = sz[l][dloc];
      sy[l][dloc] = f2bf((y + xiv * Dv) * (zv / (1.f + expf(-zv))));
    }
  }
  __syncthreads();
  for (int u = t; u < LSEQ * 16; u += 256)
    ymb[((size_t)b * LSEQ + (u >> 4)) * DIN + d0 + (u & 15)] = sy[u >> 4][u & 15];
}

// ---------------- host launch ----------------
extern "C" void kernel_launch(void* const* d_in, const int* in_sizes, int n_in,
                              void* d_out, int out_size, void* d_ws, size_t ws_size,
                              hipStream_t stream) {
  const float* nb     = (const float*)d_in[0];
  const float* center = (const float*)d_in[1];
  const void*  maskp  = d_in[2];
  const float* c1w    = (const float*)d_in[3];
  const float* c1b    = (const float*)d_in[4];
  const float* bng    = (const float*)d_in[5];
  const float* bnb    = (const float*)d_in[6];
  const float* bnm    = (const float*)d_in[7];
  const float* bnv    = (const float*)d_in[8];
  const float* c2w    = (const float*)d_in[9];
  const float* c2b    = (const float*)d_in[10];
  const float* pw1    = (const float*)d_in[11];
  const float* pb1    = (const float*)d_in[12];
  const float* pw2    = (const float*)d_in[13];
  const float* pb2    = (const float*)d_in[14];
  const float* ipw    = (const float*)d_in[15];
  const float* cw     = (const float*)d_in[16];
  const float* cb     = (const float*)d_in[17];
  const float* xpw    = (const float*)d_in[18];
  const float* dpw    = (const float*)d_in[19];
  const float* dpb    = (const float*)d_in[20];
  const float* alog   = (const float*)d_in[21];
  const float* Dp     = (const float*)d_in[22];
  const float* opw    = (const float*)d_in[23];
  const float* lnw    = (const float*)d_in[24];
  const float* lnb    = (const float*)d_in[25];
  const float* nfw    = (const float*)d_in[26];
  const float* nfb    = (const float*)d_in[27];
  const float* n2w    = (const float*)d_in[28];
  const float* n2b    = (const float*)d_in[29];
  float* out = (float*)d_out;

  char* wsb = (char*)d_ws;
  size_t off = 0;
  auto alloc = [&](size_t bytes) -> void* {
    void* ptr = (void*)(wsb + off);
    off += ((bytes + 255) & ~(size_t)255);
    return ptr;
  };
  int*   vis   = (int*)alloc(NTOK * 4);
  float* fg    = (float*)alloc((size_t)NTOK * NBK * 4);
  float* basep = (float*)alloc((size_t)NTOK * C1 * 4);
  float* h     = (float*)alloc((size_t)NTOK * DMODEL * 4);
  float* res   = (float*)alloc((size_t)NTOK * DMODEL * 4);
  float* mc    = (float*)alloc((size_t)NTOK * 3 * 4);
  float* t1    = (float*)alloc((size_t)NTOK * 128 * 4);
  short* c1lo  = (short*)alloc((size_t)C1 * NBK * 2);
  short* c1hi  = (short*)alloc((size_t)C1 * NBK * 2);
  short* c2wb  = (short*)alloc((size_t)DMODEL * F1K * 2);
  short* pw1b  = (short*)alloc((size_t)128 * 32 * 2);
  // overlap region: encoder chunk buffers vs mamba activations (disjoint in time)
  size_t regionBytes = (size_t)CHR * NBK * 2 + (size_t)CHR * F1K * 2;  // 22.8 MB
  char* region = (char*)alloc(regionBytes);
  // encoder phase
  short* nbg = (short*)region;
  short* f1  = (short*)(region + (size_t)CHR * NBK * 2);
  // mamba phase (all within region; high-water ~12 MB < 22.8 MB)
  size_t roff = 0;
  auto ralloc = [&](size_t bytes) -> void* {
    void* ptr = (void*)(region + roff);
    roff += ((bytes + 255) & ~(size_t)255);
    return ptr;
  };
  float* xz   = (float*)ralloc((size_t)NTOK * 1536 * 4);
  float* xic  = (float*)ralloc((size_t)NTOK * DIN * 4);
  float* dbl  = (float*)ralloc((size_t)NTOK * 64 * 4);
  short* xicb = (short*)ralloc((size_t)NTOK * DIN * 2);
  short* hnb  = (short*)ralloc((size_t)NTOK * DMODEL * 2);
  short* ymb  = (short*)ralloc((size_t)NTOK * DIN * 2);
  short* xpwb = (short*)ralloc((size_t)12 * 56 * DIN * 2);

  // adaptive: big bf16 weight caches for in_proj / out_proj if ws allows
  size_t ipwN = (size_t)12 * 2 * DIN * DMODEL;   // 7.08M elems
  size_t opwN = (size_t)12 * DMODEL * DIN;       // 3.54M elems
  bool useBW = (off + (ipwN + opwN) * 2 + 512 <= ws_size);
  short* ipwb = nullptr;
  short* opwb = nullptr;
  if (useBW) {
    ipwb = (short*)alloc(ipwN * 2);
    opwb = (short*)alloc(opwN * 2);
  }

  vis_kernel2<<<1, 512, 0, stream>>>(maskp, vis, out);

  // weight converts
  cvt_pad<<<(C1 * NBK + 255) / 256, 256, 0, stream>>>(c1w, C1, 0, c1lo, C1, FEAT, NBK);
  cvt_pad<<<(C1 * NBK + 255) / 256, 256, 0, stream>>>(c1w, C1, FEAT, c1hi, C1, FEAT, NBK);
  cvt_pad<<<(DMODEL * F1K + 255) / 256, 256, 0, stream>>>(c2w, C1, 0, c2wb, DMODEL, C1, F1K);
  cvt_pad<<<(128 * 32 + 255) / 256, 256, 0, stream>>>(pw1, 3, 0, pw1b, 128, 3, 32);
  if (useBW) {
    cvt_vec4<<<(int)((ipwN / 4 + 255) / 256), 256, 0, stream>>>(ipw, ipwb, (int)(ipwN / 4));
    cvt_vec4<<<(int)((opwN / 4 + 255) / 256), 256, 0, stream>>>(opw, opwb, (int)(opwN / 4));
  }

  GemmP z{};
  // encoder: 2 chunks of 412 groups
  for (int c = 0; c < 2; ++c) {
    int g0 = c * CHG;
    gather_fg<<<CHG, 320, 0, stream>>>(nb, vis, g0, nbg, fg);
    {
      GemmP p = z;
      p.A = fg + (size_t)g0 * NBK; p.lda = NBK;
      p.Bbf = c1lo; p.ldb = NBK; p.bias = c1b;
      p.C = basep + (size_t)g0 * C1; p.ldc = C1;
      p.M = CHG; p.N = C1; p.K = NBK; p.Kp = NBK;
      gemm_mfma<EP_BIAS | EP_BBF16, 64><<<dim3(5, 7), 256, 0, stream>>>(p);
    }
    {
      GemmP p = z;
      p.Abf = nbg; p.lda = NBK;
      p.Bbf = c1hi; p.ldb = NBK;
      p.M = CHR; p.N = C1; p.K = NBK; p.Kp = NBK; p.g0 = g0;
      p.bng = bng; p.bnb = bnb; p.bnm = bnm; p.bnv = bnv;
      p.basep = basep; p.f1 = f1;
      gemm_mfma<EP_ENC1 | EP_ABF16 | EP_BBF16, 128><<<dim3(5, 103), 256, 0, stream>>>(p);
    }
    {
      GemmP p = z;
      p.Abf = f1; p.lda = F1K;
      p.Bbf = c2wb; p.ldb = F1K; p.bias = c2b;
      p.C = h; p.ldc = DMODEL;
      p.M = CHR; p.N = DMODEL; p.K = F1K; p.Kp = F1K; p.g0 = g0;
      gemm_mfma<EP_POOL | EP_ABF16 | EP_BBF16, 64><<<dim3(3, 206), 256, 0, stream>>>(p);
    }
  }

  // positional embedding accumulated into h
  gather_mc<<<(NTOK * 3 + 255) / 256, 256, 0, stream>>>(center, vis, mc);
  {
    GemmP p = z;
    p.A = mc; p.lda = 3;
    p.Bbf = pw1b; p.ldb = 32; p.bias = pb1;
    p.C = t1; p.ldc = 128;
    p.M = NTOK; p.N = 128; p.K = 3; p.Kp = 32;
    gemm_mfma<EP_BIAS | EP_GELU | EP_BBF16, 64><<<dim3(1, 13), 256, 0, stream>>>(p);
  }
  {
    GemmP p = z;
    p.A = t1; p.lda = 128;
    p.B = pw2; p.ldb = 128; p.bias = pb2;
    p.C = h; p.ldc = DMODEL;
    p.M = NTOK; p.N = DMODEL; p.K = 128; p.Kp = 128;
    gemm_mfma<EP_BIAS | EP_ACCUM, 64><<<dim3(3, 13), 256, 0, stream>>>(p);
  }

  // x_proj weights -> bf16 (after encoder: region reuse is now safe)
  cvt_vec4<<<(12 * 56 * DIN / 4 + 255) / 256, 256, 0, stream>>>(xpw, xpwb, 12 * 56 * DIN / 4);

  for (int i = 0; i < 12; ++i) {
    ln4_kernel<<<(NTOK + 3) / 4, 256, 0, stream>>>(h, res, res, hnb, lnw + i * DMODEL,
                                                   lnb + i * DMODEL, i > 0 ? 1 : 0);
    if (useBW) {
      GemmP p = z;
      p.Abf = hnb; p.lda = DMODEL;
      p.Bbf = ipwb + (size_t)i * 2 * DIN * DMODEL; p.ldb = DMODEL;
      p.C = xz; p.ldc = 2 * DIN;
      p.M = NTOK; p.N = 2 * DIN; p.K = DMODEL; p.Kp = DMODEL;
      gemm_mfma<EP_ABF16 | EP_BBF16, 64><<<dim3(12, 13), 256, 0, stream>>>(p);
    } else {
      GemmP p = z;
      p.Abf = hnb; p.lda = DMODEL;
      p.B = ipw + (size_t)i * 2 * DIN * DMODEL; p.ldb = DMODEL;
      p.C = xz; p.ldc = 2 * DIN;
      p.M = NTOK; p.N = 2 * DIN; p.K = DMODEL; p.Kp = DMODEL;
      gemm_mfma<EP_ABF16, 64><<<dim3(12, 13), 256, 0, stream>>>(p);
    }
    conv_silu<<<(NTOK * (DIN / 4) + 255) / 256, 256, 0, stream>>>(
        xz, cw + (size_t)i * DIN * 4, cb + (size_t)i * DIN, xic, xicb);
    {
      GemmP p = z;
      p.Abf = xicb; p.lda = DIN;
      p.Bbf = xpwb + (size_t)i * 56 * DIN; p.ldb = DIN;
      p.C = dbl; p.ldc = 56;
      p.M = NTOK; p.N = 56; p.K = DIN; p.Kp = DIN;
      gemm_mfma<EP_ABF16 | EP_BBF16, 64><<<dim3(1, 13), 256, 0, stream>>>(p);
    }
    scan_fused<<<384, 256, 0, stream>>>(dbl, xic, xz, dpw + (size_t)i * DIN * 24,
                                        dpb + (size_t)i * DIN,
                                        alog + (size_t)i * DIN * 16,
                                        Dp + (size_t)i * DIN, ymb);
    if (useBW) {
      GemmP p = z;
      p.Abf = ymb; p.lda = DIN;
      p.Bbf = opwb + (size_t)i * DMODEL * DIN; p.ldb = DIN;
      p.C = h; p.ldc = DMODEL;
      p.M = NTOK; p.N = DMODEL; p.K = DIN; p.Kp = DIN;
      gemm_mfma<EP_ABF16 | EP_BBF16, 64><<<dim3(3, 13), 256, 0, stream>>>(p);
    } else {
      GemmP p = z;
      p.Abf = ymb; p.lda = DIN;
      p.B = opw + (size_t)i * DMODEL * DIN; p.ldb = DIN;
      p.C = h; p.ldc = DMODEL;
      p.M = NTOK; p.N = DMODEL; p.K = DIN; p.Kp = DIN;
      gemm_mfma<EP_ABF16, 64><<<dim3(3, 13), 256, 0, stream>>>(p);
    }
  }

  final_kernel<<<NTOK, 64, 0, stream>>>(h, res, nfw, nfb, n2w, n2b, out);
}

// Round 10
// 1528.612 us; speedup vs baseline: 3.4348x; 1.0938x over previous
//
#include <hip/hip_runtime.h>
#include <math.h>

#define GVIS 103
#define BB 8
#define GG 256
#define NPT 32
#define FEAT 273
#define C1 546
#define DMODEL 384
#define DIN 768
#define LSEQ 103
#define NTOK 824
#define EPSV 1e-5f
#define NBK 288          // padded K for point features (273->288)
#define F1K 576          // padded K for f1 (546->576)
#define CHG 412          // groups per encoder chunk
#define CHR (CHG * 32)   // rows per encoder chunk

typedef __attribute__((ext_vector_type(8))) short s16x8;
typedef __attribute__((ext_vector_type(4))) short s16x4;
typedef __attribute__((ext_vector_type(4))) float f32x4;

enum {
  EP_BIAS = 1, EP_GELU = 2, EP_ACCUM = 4, EP_ENC1 = 8, EP_POOL = 16,
  EP_ABF16 = 32, EP_BBF16 = 64
};

__device__ __forceinline__ short f2bf(float f) {
  unsigned u = __builtin_bit_cast(unsigned, f);
  u += 0x7fffu + ((u >> 16) & 1u);
  return (short)(u >> 16);
}

struct GemmP {
  const float* A; int lda;
  const short* Abf;
  const float* B; int ldb;
  const short* Bbf;
  const float* bias;
  float* C; int ldc;
  short* f1;
  int M, N, K, Kp, g0;
  const float* bng; const float* bnb; const float* bnm; const float* bnv;
  const float* basep;
};

// ---------------- MFMA GEMM: C[M,N] = A[M,K] * B[N,K]^T ----------------
// TM=128: 4 waves as 2x2 (64x64 each). TM=64: 4 waves as 1x4 (64x32 each).
template <int MODE, int TM>
__global__ __launch_bounds__(256) void gemm_mfma(GemmP p) {
  __shared__ short As[TM * 40];
  __shared__ short Bs[128 * 40];
  constexpr int WC = (TM == 128) ? 2 : 4;
  constexpr int NF = 128 / (WC * 16);
  const int t = threadIdx.x;
  const int m0 = blockIdx.y * TM, n0 = blockIdx.x * 128;
  const int srow = t >> 1, skh = (t & 1) * 16;
  const int lane = t & 63, wave = t >> 6;
  const int wr = wave / WC, wc = wave % WC;
  const int lrow = lane & 15, lk = (lane >> 4) * 8;

  const bool aRowIn = (TM == 128) ? true : (t < 128);
  const int arow = m0 + srow;
  const bool aValid = aRowIn && (arow < p.M);
  const bool bValid = (n0 + srow) < p.N;
  const float* aPtr = nullptr; const short* aPtrB = nullptr;
  if constexpr (MODE & EP_ABF16) { if (aValid) aPtrB = p.Abf + (size_t)arow * p.lda; }
  else { if (aValid) aPtr = p.A + (size_t)arow * p.lda; }
  const float* bPtrF = nullptr; const short* bPtrB = nullptr;
  if constexpr (MODE & EP_BBF16) { if (bValid) bPtrB = p.Bbf + (size_t)(n0 + srow) * p.ldb; }
  else { if (bValid) bPtrF = p.B + (size_t)(n0 + srow) * p.ldb; }
  const bool avec = ((p.lda & 3) == 0) && (p.K == p.Kp);
  const bool bvec = ((p.ldb & 3) == 0) && (p.K == p.Kp);

  f32x4 acc[4][NF];
#pragma unroll
  for (int i = 0; i < 4; ++i)
#pragma unroll
    for (int j = 0; j < NF; ++j) acc[i][j] = f32x4{0.f, 0.f, 0.f, 0.f};

  for (int k0 = 0; k0 < p.Kp; k0 += 32) {
    // ---- stage A ----
    if (aRowIn) {
      s16x8 q0 = {}, q1 = {};
      if (aValid) {
        if constexpr (MODE & EP_ABF16) {
          q0 = *(const s16x8*)(aPtrB + k0 + skh);
          q1 = *(const s16x8*)(aPtrB + k0 + skh + 8);
        } else {
          float v[16];
          if (avec) {
            f32x4 f0 = *(const f32x4*)(aPtr + k0 + skh);
            f32x4 f1v = *(const f32x4*)(aPtr + k0 + skh + 4);
            f32x4 f2v = *(const f32x4*)(aPtr + k0 + skh + 8);
            f32x4 f3v = *(const f32x4*)(aPtr + k0 + skh + 12);
#pragma unroll
            for (int j = 0; j < 4; ++j) {
              v[j] = f0[j]; v[j + 4] = f1v[j]; v[j + 8] = f2v[j]; v[j + 12] = f3v[j];
            }
          } else {
#pragma unroll
            for (int j = 0; j < 16; ++j) {
              int k = k0 + skh + j;
              v[j] = (k < p.K) ? aPtr[k] : 0.f;
            }
          }
#pragma unroll
          for (int j = 0; j < 8; ++j) { q0[j] = f2bf(v[j]); q1[j] = f2bf(v[j + 8]); }
        }
      }
      *(s16x8*)(As + srow * 40 + skh) = q0;
      *(s16x8*)(As + srow * 40 + skh + 8) = q1;
    }
    // ---- stage B ----
    {
      s16x8 q0 = {}, q1 = {};
      if (bValid) {
        if constexpr (MODE & EP_BBF16) {
          q0 = *(const s16x8*)(bPtrB + k0 + skh);
          q1 = *(const s16x8*)(bPtrB + k0 + skh + 8);
        } else {
          float v[16];
          if (bvec) {
            f32x4 f0 = *(const f32x4*)(bPtrF + k0 + skh);
            f32x4 f1v = *(const f32x4*)(bPtrF + k0 + skh + 4);
            f32x4 f2v = *(const f32x4*)(bPtrF + k0 + skh + 8);
            f32x4 f3v = *(const f32x4*)(bPtrF + k0 + skh + 12);
#pragma unroll
            for (int j = 0; j < 4; ++j) {
              v[j] = f0[j]; v[j + 4] = f1v[j]; v[j + 8] = f2v[j]; v[j + 12] = f3v[j];
            }
          } else {
#pragma unroll
            for (int j = 0; j < 16; ++j) {
              int k = k0 + skh + j;
              v[j] = (k < p.K) ? bPtrF[k] : 0.f;
            }
          }
#pragma unroll
          for (int j = 0; j < 8; ++j) { q0[j] = f2bf(v[j]); q1[j] = f2bf(v[j + 8]); }
        }
      }
      *(s16x8*)(Bs + srow * 40 + skh) = q0;
      *(s16x8*)(Bs + srow * 40 + skh + 8) = q1;
    }
    __syncthreads();
    s16x8 af[4], bfr[NF];
#pragma unroll
    for (int f = 0; f < 4; ++f)
      af[f] = *(const s16x8*)(As + (wr * 64 + f * 16 + lrow) * 40 + lk);
#pragma unroll
    for (int f = 0; f < NF; ++f)
      bfr[f] = *(const s16x8*)(Bs + (wc * (NF * 16) + f * 16 + lrow) * 40 + lk);
#pragma unroll
    for (int i = 0; i < 4; ++i)
#pragma unroll
      for (int j = 0; j < NF; ++j)
        acc[i][j] = __builtin_amdgcn_mfma_f32_16x16x32_bf16(af[i], bfr[j], acc[i][j], 0, 0, 0);
    __syncthreads();
  }

  // ---------------- epilogues ----------------
  if constexpr (MODE & EP_POOL) {
#pragma unroll
    for (int g2 = 0; g2 < 2; ++g2) {
#pragma unroll
      for (int fn = 0; fn < NF; ++fn) {
        float mx = -3.4e38f;
#pragma unroll
        for (int fm = 2 * g2; fm < 2 * g2 + 2; ++fm)
#pragma unroll
          for (int r = 0; r < 4; ++r) mx = fmaxf(mx, acc[fm][fn][r]);
        mx = fmaxf(mx, __shfl_xor(mx, 16));
        mx = fmaxf(mx, __shfl_xor(mx, 32));
        if ((lane >> 4) == 0) {
          int gi = p.g0 + ((m0 + wr * 64 + g2 * 32) >> 5);
          int o = n0 + wc * (NF * 16) + fn * 16 + lane;
          p.C[(size_t)gi * p.ldc + o] = mx + p.bias[o];
        }
      }
    }
  } else if constexpr (MODE & EP_ENC1) {
#pragma unroll
    for (int fm = 0; fm < 4; ++fm) {
      int mbase = m0 + wr * 64 + fm * 16 + (lane >> 4) * 4;
#pragma unroll
      for (int fn = 0; fn < NF; ++fn) {
        int o = n0 + wc * (NF * 16) + fn * 16 + lrow;
        if (o >= F1K) continue;
        if (o < C1) {
          float sc = p.bng[o] * rsqrtf(p.bnv[o] + EPSV);
          float sh = p.bnb[o] - p.bnm[o] * sc;
#pragma unroll
          for (int r = 0; r < 4; ++r) {
            int mm = mbase + r;
            int gi = p.g0 + (mm >> 5);
            float v = acc[fm][fn][r] + p.basep[(size_t)gi * C1 + o];
            p.f1[(size_t)mm * F1K + o] = f2bf(fmaxf(v * sc + sh, 0.f));
          }
        } else {
#pragma unroll
          for (int r = 0; r < 4; ++r) p.f1[(size_t)(mbase + r) * F1K + o] = 0;
        }
      }
    }
  } else {
#pragma unroll
    for (int fm = 0; fm < 4; ++fm) {
#pragma unroll
      for (int fn = 0; fn < NF; ++fn) {
        int o = n0 + wc * (NF * 16) + fn * 16 + lrow;
        if (o >= p.N) continue;
#pragma unroll
        for (int r = 0; r < 4; ++r) {
          int m = m0 + wr * 64 + fm * 16 + (lane >> 4) * 4 + r;
          if (m >= p.M) continue;
          float v = acc[fm][fn][r];
          if (MODE & EP_BIAS) v += p.bias[o];
          if (MODE & EP_GELU) v = 0.5f * v * (1.f + erff(v * 0.70710678118f));
          if (MODE & EP_ACCUM) v += p.C[(size_t)m * p.ldc + o];
          p.C[(size_t)m * p.ldc + o] = v;
        }
      }
    }
  }
}

// ---------------- weight convert/pad fp32 -> bf16 (padded rows) ----------------
__global__ void cvt_pad(const float* __restrict__ src, int srcld, int colOff,
                        short* __restrict__ dst, int nrows, int Kv, int Kp) {
  int idx = blockIdx.x * 256 + threadIdx.x;
  if (idx >= nrows * Kp) return;
  int r = idx / Kp, k = idx - r * Kp;
  dst[idx] = (k < Kv) ? f2bf(src[(size_t)r * srcld + colOff + k]) : (short)0;
}

// ---------------- contiguous vectorized fp32 -> bf16 ----------------
__global__ void cvt_vec4(const float* __restrict__ src, short* __restrict__ dst, int n4) {
  int i = blockIdx.x * 256 + threadIdx.x;
  if (i >= n4) return;
  f32x4 v = ((const f32x4*)src)[i];
  s16x4 o;
#pragma unroll
  for (int j = 0; j < 4; ++j) o[j] = f2bf(v[j]);
  ((s16x4*)dst)[i] = o;
}

// ---------------- parallel vis list + mask dtype detect + mask echo ----------------
__global__ __launch_bounds__(512) void vis_kernel2(const void* maskp, int* vis,
                                                   float* out) {
  __shared__ int red[8];
  __shared__ int isIntSh;
  int t = threadIdx.x;
  const unsigned char* bp = (const unsigned char*)maskp;
  const int* ip = (const int*)maskp;
  // dtype detect: int32 iff all bytes at (i&3)!=0 are zero
  int s = 0;
  for (int i = t; i < BB * GG; i += 512) if (i & 3) s += bp[i];
  for (int o = 32; o; o >>= 1) s += __shfl_xor(s, o);
  if ((t & 63) == 0) red[t >> 6] = s;
  __syncthreads();
  if (t == 0) {
    int tot = 0;
    for (int w = 0; w < 8; ++w) tot += red[w];
    isIntSh = (tot == 0) ? 1 : 0;
  }
  __syncthreads();
  int isInt = isIntSh;
  // mask echo into output tail
  for (int i = t; i < BB * GG; i += 512) {
    int mv = isInt ? ip[i] : (int)bp[i];
    out[NTOK * DMODEL + i] = mv ? 1.f : 0.f;
  }
  // visible-list: wave w = batch w; lane owns 4 contiguous groups
  int w = t >> 6, lane = t & 63;
  int cnt = 0;
  int gs[4];
#pragma unroll
  for (int j = 0; j < 4; ++j) {
    int g = lane * 4 + j;
    int mv = isInt ? ip[w * GG + g] : (int)bp[w * GG + g];
    if (!mv) gs[cnt++] = g;
  }
  int inc = cnt;
  for (int o = 1; o < 64; o <<= 1) {
    int v = __shfl_up(inc, o);
    if (lane >= o) inc += v;
  }
  int base = inc - cnt;
  for (int j = 0; j < cnt; ++j) {
    int pos = base + j;
    if (pos < GVIS) vis[w * GVIS + pos] = gs[j];
  }
  int total = __shfl(inc, 63);
  for (int pos = total + lane; pos < GVIS; pos += 64) vis[w * GVIS + pos] = 0;
}

// ---------------- gather visible groups -> compact bf16 + per-group max ----------------
__global__ __launch_bounds__(320) void gather_fg(const float* __restrict__ nb,
                                                 const int* __restrict__ vis, int g0,
                                                 short* __restrict__ nbg,
                                                 float* __restrict__ fg) {
  int gl = blockIdx.x;
  int gi = g0 + gl;
  int c = threadIdx.x;
  if (c >= NBK) return;
  int b = gi / GVIS;
  int g = vis[gi];
  size_t base = ((size_t)(b * GG + g)) * NPT * FEAT;
  size_t orow = (size_t)gl * 32;
  if (c < FEAT) {
    float mx = -3.4e38f;
#pragma unroll 4
    for (int r = 0; r < 32; ++r) {
      float v = nb[base + (size_t)r * FEAT + c];
      mx = fmaxf(mx, v);
      nbg[(orow + r) * NBK + c] = f2bf(v);
    }
    fg[(size_t)gi * NBK + c] = mx;
  } else {
    for (int r = 0; r < 32; ++r) nbg[(orow + r) * NBK + c] = 0;
    fg[(size_t)gi * NBK + c] = 0.f;
  }
}

// ---------------- center gather ----------------
__global__ void gather_mc(const float* __restrict__ center, const int* __restrict__ vis,
                          float* __restrict__ mc) {
  int i = blockIdx.x * 256 + threadIdx.x;
  if (i >= NTOK * 3) return;
  int tok = i / 3, c = i - tok * 3;
  int b = tok / GVIS;
  int g = vis[tok];
  mc[i] = center[((size_t)b * GG + g) * 3 + c];
}

// ---------------- layernorm: 4 tokens/block, bf16 output for GEMM A ----------------
__device__ __forceinline__ float wave_sum(float x) {
  for (int o = 32; o; o >>= 1) x += __shfl_xor(x, o);
  return x;
}

__global__ __launch_bounds__(256) void ln4_kernel(
    const float* __restrict__ h, const float* __restrict__ res_in,
    float* __restrict__ res_out, short* __restrict__ hnb,
    const float* __restrict__ w, const float* __restrict__ b, int add) {
  int tok = blockIdx.x * 4 + (threadIdx.x >> 6);
  int lane = threadIdx.x & 63;
  if (tok >= NTOK) return;
  const float* hr = h + (size_t)tok * DMODEL;
  float v[6];
#pragma unroll
  for (int j = 0; j < 6; ++j) {
    int c = lane + j * 64;
    float x = hr[c];
    if (add) x += res_in[(size_t)tok * DMODEL + c];
    v[j] = x;
  }
  float s = 0.f;
#pragma unroll
  for (int j = 0; j < 6; ++j) s += v[j];
  s = wave_sum(s);
  float mu = s * (1.f / DMODEL);
  float q = 0.f;
#pragma unroll
  for (int j = 0; j < 6; ++j) { float d = v[j] - mu; q += d * d; }
  q = wave_sum(q);
  float rstd = rsqrtf(q * (1.f / DMODEL) + EPSV);
#pragma unroll
  for (int j = 0; j < 6; ++j) {
    int c = lane + j * 64;
    res_out[(size_t)tok * DMODEL + c] = v[j];
    hnb[(size_t)tok * DMODEL + c] = f2bf((v[j] - mu) * rstd * w[c] + b[c]);
  }
}

__global__ __launch_bounds__(64) void final_kernel(
    const float* __restrict__ h, const float* __restrict__ res,
    const float* __restrict__ w1, const float* __restrict__ b1,
    const float* __restrict__ w2, const float* __restrict__ b2,
    float* __restrict__ out) {
  int tok = blockIdx.x, lane = threadIdx.x;
  float v[6];
#pragma unroll
  for (int j = 0; j < 6; ++j) {
    int c = lane + j * 64;
    v[j] = h[(size_t)tok * DMODEL + c] + res[(size_t)tok * DMODEL + c];
  }
  float s = 0.f;
#pragma unroll
  for (int j = 0; j < 6; ++j) s += v[j];
  s = wave_sum(s);
  float mu = s * (1.f / DMODEL);
  float q = 0.f;
#pragma unroll
  for (int j = 0; j < 6; ++j) { float d = v[j] - mu; q += d * d; }
  q = wave_sum(q);
  float rstd = rsqrtf(q * (1.f / DMODEL) + EPSV);
#pragma unroll
  for (int j = 0; j < 6; ++j) {
    int c = lane + j * 64;
    v[j] = (v[j] - mu) * rstd * w1[c] + b1[c];
  }
  s = 0.f;
#pragma unroll
  for (int j = 0; j < 6; ++j) s += v[j];
  s = wave_sum(s);
  mu = s * (1.f / DMODEL);
  q = 0.f;
#pragma unroll
  for (int j = 0; j < 6; ++j) { float d = v[j] - mu; q += d * d; }
  q = wave_sum(q);
  rstd = rsqrtf(q * (1.f / DMODEL) + EPSV);
#pragma unroll
  for (int j = 0; j < 6; ++j) {
    int c = lane + j * 64;
    out[(size_t)tok * DMODEL + c] = (v[j] - mu) * rstd * w2[c] + b2[c];
  }
}

// ---------------- causal depthwise conv (k=4) + silu, vectorized x4 ----------------
__global__ __launch_bounds__(256) void conv_silu(const float* __restrict__ xz,
                                                 const float* __restrict__ cw,
                                                 const float* __restrict__ cb,
                                                 float* __restrict__ xic,
                                                 short* __restrict__ xicb) {
  int idx = blockIdx.x * 256 + threadIdx.x;   // one thread = 4 channels of one token
  if (idx >= NTOK * (DIN / 4)) return;
  int tok = idx / (DIN / 4);
  int c4 = (idx - tok * (DIN / 4)) * 4;
  int b = tok / LSEQ, l = tok - b * LSEQ;
  f32x4 cwv[4];
#pragma unroll
  for (int j = 0; j < 4; ++j) cwv[j] = *(const f32x4*)(cw + (size_t)(c4 + j) * 4);
  f32x4 sv = *(const f32x4*)(cb + c4);
#pragma unroll
  for (int k = 0; k < 4; ++k) {
    int ls = l - 3 + k;
    if (ls < 0) continue;
    f32x4 xv = *(const f32x4*)(xz + (size_t)(b * LSEQ + ls) * (2 * DIN) + c4);
#pragma unroll
    for (int e = 0; e < 4; ++e) sv[e] = fmaf(cwv[e][k], xv[e], sv[e]);
  }
  s16x4 ob;
#pragma unroll
  for (int e = 0; e < 4; ++e) {
    sv[e] = sv[e] / (1.f + expf(-sv[e]));
    ob[e] = f2bf(sv[e]);
  }
  *(f32x4*)(xic + (size_t)tok * DIN + c4) = sv;
  *(s16x4*)(xicb + (size_t)tok * DIN + c4) = ob;
}

// ---------------- fused dt_proj + selective scan, ILP-unrolled recurrence ----------------
#define SCAN_STEPS(U)                                                         \
  {                                                                           \
    float dAr[U], dBr[U], yv[U];                                              \
    _Pragma("unroll") for (int u = 0; u < U; ++u) {                           \
      int l = l0 + u;                                                         \
      float dtv = sdt[l][dloc];                                               \
      dAr[u] = expf(dtv * Av);                                                \
      dBr[u] = dtv * sxi[l][dloc] * sdbl[l][24 + s];                          \
    }                                                                         \
    _Pragma("unroll") for (int u = 0; u < U; ++u) {                           \
      hst = fmaf(dAr[u], hst, dBr[u]);                                        \
      yv[u] = hst * sdbl[l0 + u][40 + s];                                     \
    }                                                                         \
    _Pragma("unroll") for (int u = 0; u < U; ++u) yv[u] += __shfl_xor(yv[u], 1); \
    _Pragma("unroll") for (int u = 0; u < U; ++u) yv[u] += __shfl_xor(yv[u], 2); \
    _Pragma("unroll") for (int u = 0; u < U; ++u) yv[u] += __shfl_xor(yv[u], 4); \
    _Pragma("unroll") for (int u = 0; u < U; ++u) yv[u] += __shfl_xor(yv[u], 8); \
    if (s == 0) {                                                             \
      _Pragma("unroll") for (int u = 0; u < U; ++u) {                         \
        int l = l0 + u;                                                       \
        float xiv = sxi[l][dloc];                                             \
        float zv = sz[l][dloc];                                               \
        sy[l][dloc] = f2bf((yv[u] + xiv * Dv) * (zv / (1.f + expf(-zv))));    \
      }                                                                       \
    }                                                                         \
  }

__global__ __launch_bounds__(256) void scan_fused(
    const float* __restrict__ dbl, const float* __restrict__ xic,
    const float* __restrict__ xz, const float* __restrict__ dpw,
    const float* __restrict__ dpb, const float* __restrict__ alog,
    const float* __restrict__ Dp, short* __restrict__ ymb) {
  __shared__ float sdbl[LSEQ][56];
  __shared__ float sdt[LSEQ][16];
  __shared__ float sxi[LSEQ][16];
  __shared__ float sz[LSEQ][16];
  __shared__ short sy[LSEQ][16];
  int t = threadIdx.x;
  int b = blockIdx.x / 48, chunk = blockIdx.x % 48;
  int d0 = chunk * 16;
  for (int u = t; u < LSEQ * 56; u += 256) {
    int l = u / 56, cc = u - l * 56;
    sdbl[l][cc] = dbl[((size_t)b * LSEQ + l) * 56 + cc];
  }
  for (int u = t; u < LSEQ * 16; u += 256) {
    int l = u >> 4, dl = u & 15;
    sxi[l][dl] = xic[((size_t)b * LSEQ + l) * DIN + d0 + dl];
    sz[l][dl] = xz[((size_t)b * LSEQ + l) * (2 * DIN) + DIN + d0 + dl];
  }
  __syncthreads();
  for (int u = t; u < LSEQ * 16; u += 256) {
    int l = u >> 4, dl = u & 15;
    const float* wp = dpw + (size_t)(d0 + dl) * 24;
    float sacc = dpb[d0 + dl];
#pragma unroll
    for (int kk = 0; kk < 24; ++kk) sacc = fmaf(wp[kk], sdbl[l][kk], sacc);
    sdt[l][dl] = (sacc > 20.f) ? sacc : log1pf(expf(sacc));
  }
  __syncthreads();
  int s = t & 15, dloc = t >> 4;
  int d = d0 + dloc;
  float Av = -expf(alog[(size_t)d * 16 + s]);
  float Dv = Dp[d];
  float hst = 0.f;
  int l0 = 0;
  for (; l0 + 8 <= LSEQ; l0 += 8) SCAN_STEPS(8);
  SCAN_STEPS(7);   // tail: l0 = 96, covers 96..102
  __syncthreads();
  for (int u = t; u < LSEQ * 16; u += 256)
    ymb[((size_t)b * LSEQ + (u >> 4)) * DIN + d0 + (u & 15)] = sy[u >> 4][u & 15];
}

// ---------------- host launch ----------------
extern "C" void kernel_launch(void* const* d_in, const int* in_sizes, int n_in,
                              void* d_out, int out_size, void* d_ws, size_t ws_size,
                              hipStream_t stream) {
  const float* nb     = (const float*)d_in[0];
  const float* center = (const float*)d_in[1];
  const void*  maskp  = d_in[2];
  const float* c1w    = (const float*)d_in[3];
  const float* c1b    = (const float*)d_in[4];
  const float* bng    = (const float*)d_in[5];
  const float* bnb    = (const float*)d_in[6];
  const float* bnm    = (const float*)d_in[7];
  const float* bnv    = (const float*)d_in[8];
  const float* c2w    = (const float*)d_in[9];
  const float* c2b    = (const float*)d_in[10];
  const float* pw1    = (const float*)d_in[11];
  const float* pb1    = (const float*)d_in[12];
  const float* pw2    = (const float*)d_in[13];
  const float* pb2    = (const float*)d_in[14];
  const float* ipw    = (const float*)d_in[15];
  const float* cw     = (const float*)d_in[16];
  const float* cb     = (const float*)d_in[17];
  const float* xpw    = (const float*)d_in[18];
  const float* dpw    = (const float*)d_in[19];
  const float* dpb    = (const float*)d_in[20];
  const float* alog   = (const float*)d_in[21];
  const float* Dp     = (const float*)d_in[22];
  const float* opw    = (const float*)d_in[23];
  const float* lnw    = (const float*)d_in[24];
  const float* lnb    = (const float*)d_in[25];
  const float* nfw    = (const float*)d_in[26];
  const float* nfb    = (const float*)d_in[27];
  const float* n2w    = (const float*)d_in[28];
  const float* n2b    = (const float*)d_in[29];
  float* out = (float*)d_out;

  char* wsb = (char*)d_ws;
  size_t off = 0;
  auto alloc = [&](size_t bytes) -> void* {
    void* ptr = (void*)(wsb + off);
    off += ((bytes + 255) & ~(size_t)255);
    return ptr;
  };
  int*   vis   = (int*)alloc(NTOK * 4);
  float* fg    = (float*)alloc((size_t)NTOK * NBK * 4);
  float* basep = (float*)alloc((size_t)NTOK * C1 * 4);
  float* h     = (float*)alloc((size_t)NTOK * DMODEL * 4);
  float* res   = (float*)alloc((size_t)NTOK * DMODEL * 4);
  float* mc    = (float*)alloc((size_t)NTOK * 3 * 4);
  float* t1    = (float*)alloc((size_t)NTOK * 128 * 4);
  short* c1lo  = (short*)alloc((size_t)C1 * NBK * 2);
  short* c1hi  = (short*)alloc((size_t)C1 * NBK * 2);
  short* c2wb  = (short*)alloc((size_t)DMODEL * F1K * 2);
  short* pw1b  = (short*)alloc((size_t)128 * 32 * 2);
  // overlap region: encoder chunk buffers vs mamba activations (disjoint in time)
  size_t regionBytes = (size_t)CHR * NBK * 2 + (size_t)CHR * F1K * 2;  // 22.8 MB
  char* region = (char*)alloc(regionBytes);
  // encoder phase
  short* nbg = (short*)region;
  short* f1  = (short*)(region + (size_t)CHR * NBK * 2);
  // mamba phase (all within region; high-water ~12 MB < 22.8 MB)
  size_t roff = 0;
  auto ralloc = [&](size_t bytes) -> void* {
    void* ptr = (void*)(region + roff);
    roff += ((bytes + 255) & ~(size_t)255);
    return ptr;
  };
  float* xz   = (float*)ralloc((size_t)NTOK * 1536 * 4);
  float* xic  = (float*)ralloc((size_t)NTOK * DIN * 4);
  float* dbl  = (float*)ralloc((size_t)NTOK * 64 * 4);
  short* xicb = (short*)ralloc((size_t)NTOK * DIN * 2);
  short* hnb  = (short*)ralloc((size_t)NTOK * DMODEL * 2);
  short* ymb  = (short*)ralloc((size_t)NTOK * DIN * 2);
  short* xpwb = (short*)ralloc((size_t)12 * 56 * DIN * 2);

  // adaptive: big bf16 weight caches for in_proj / out_proj if ws allows
  size_t ipwN = (size_t)12 * 2 * DIN * DMODEL;   // 7.08M elems
  size_t opwN = (size_t)12 * DMODEL * DIN;       // 3.54M elems
  bool useBW = (off + (ipwN + opwN) * 2 + 512 <= ws_size);
  short* ipwb = nullptr;
  short* opwb = nullptr;
  if (useBW) {
    ipwb = (short*)alloc(ipwN * 2);
    opwb = (short*)alloc(opwN * 2);
  }

  vis_kernel2<<<1, 512, 0, stream>>>(maskp, vis, out);

  // weight converts
  cvt_pad<<<(C1 * NBK + 255) / 256, 256, 0, stream>>>(c1w, C1, 0, c1lo, C1, FEAT, NBK);
  cvt_pad<<<(C1 * NBK + 255) / 256, 256, 0, stream>>>(c1w, C1, FEAT, c1hi, C1, FEAT, NBK);
  cvt_pad<<<(DMODEL * F1K + 255) / 256, 256, 0, stream>>>(c2w, C1, 0, c2wb, DMODEL, C1, F1K);
  cvt_pad<<<(128 * 32 + 255) / 256, 256, 0, stream>>>(pw1, 3, 0, pw1b, 128, 3, 32);
  if (useBW) {
    cvt_vec4<<<(int)((ipwN / 4 + 255) / 256), 256, 0, stream>>>(ipw, ipwb, (int)(ipwN / 4));
    cvt_vec4<<<(int)((opwN / 4 + 255) / 256), 256, 0, stream>>>(opw, opwb, (int)(opwN / 4));
  }

  GemmP z{};
  // encoder: 2 chunks of 412 groups
  for (int c = 0; c < 2; ++c) {
    int g0 = c * CHG;
    gather_fg<<<CHG, 320, 0, stream>>>(nb, vis, g0, nbg, fg);
    {
      GemmP p = z;
      p.A = fg + (size_t)g0 * NBK; p.lda = NBK;
      p.Bbf = c1lo; p.ldb = NBK; p.bias = c1b;
      p.C = basep + (size_t)g0 * C1; p.ldc = C1;
      p.M = CHG; p.N = C1; p.K = NBK; p.Kp = NBK;
      gemm_mfma<EP_BIAS | EP_BBF16, 64><<<dim3(5, 7), 256, 0, stream>>>(p);
    }
    {
      GemmP p = z;
      p.Abf = nbg; p.lda = NBK;
      p.Bbf = c1hi; p.ldb = NBK;
      p.M = CHR; p.N = C1; p.K = NBK; p.Kp = NBK; p.g0 = g0;
      p.bng = bng; p.bnb = bnb; p.bnm = bnm; p.bnv = bnv;
      p.basep = basep; p.f1 = f1;
      gemm_mfma<EP_ENC1 | EP_ABF16 | EP_BBF16, 128><<<dim3(5, 103), 256, 0, stream>>>(p);
    }
    {
      GemmP p = z;
      p.Abf = f1; p.lda = F1K;
      p.Bbf = c2wb; p.ldb = F1K; p.bias = c2b;
      p.C = h; p.ldc = DMODEL;
      p.M = CHR; p.N = DMODEL; p.K = F1K; p.Kp = F1K; p.g0 = g0;
      gemm_mfma<EP_POOL | EP_ABF16 | EP_BBF16, 64><<<dim3(3, 206), 256, 0, stream>>>(p);
    }
  }

  // positional embedding accumulated into h
  gather_mc<<<(NTOK * 3 + 255) / 256, 256, 0, stream>>>(center, vis, mc);
  {
    GemmP p = z;
    p.A = mc; p.lda = 3;
    p.Bbf = pw1b; p.ldb = 32; p.bias = pb1;
    p.C = t1; p.ldc = 128;
    p.M = NTOK; p.N = 128; p.K = 3; p.Kp = 32;
    gemm_mfma<EP_BIAS | EP_GELU | EP_BBF16, 64><<<dim3(1, 13), 256, 0, stream>>>(p);
  }
  {
    GemmP p = z;
    p.A = t1; p.lda = 128;
    p.B = pw2; p.ldb = 128; p.bias = pb2;
    p.C = h; p.ldc = DMODEL;
    p.M = NTOK; p.N = DMODEL; p.K = 128; p.Kp = 128;
    gemm_mfma<EP_BIAS | EP_ACCUM, 64><<<dim3(3, 13), 256, 0, stream>>>(p);
  }

  // x_proj weights -> bf16 (after encoder: region reuse is now safe)
  cvt_vec4<<<(12 * 56 * DIN / 4 + 255) / 256, 256, 0, stream>>>(xpw, xpwb, 12 * 56 * DIN / 4);

  for (int i = 0; i < 12; ++i) {
    ln4_kernel<<<(NTOK + 3) / 4, 256, 0, stream>>>(h, res, res, hnb, lnw + i * DMODEL,
                                                   lnb + i * DMODEL, i > 0 ? 1 : 0);
    if (useBW) {
      GemmP p = z;
      p.Abf = hnb; p.lda = DMODEL;
      p.Bbf = ipwb + (size_t)i * 2 * DIN * DMODEL; p.ldb = DMODEL;
      p.C = xz; p.ldc = 2 * DIN;
      p.M = NTOK; p.N = 2 * DIN; p.K = DMODEL; p.Kp = DMODEL;
      gemm_mfma<EP_ABF16 | EP_BBF16, 64><<<dim3(12, 13), 256, 0, stream>>>(p);
    } else {
      GemmP p = z;
      p.Abf = hnb; p.lda = DMODEL;
      p.B = ipw + (size_t)i * 2 * DIN * DMODEL; p.ldb = DMODEL;
      p.C = xz; p.ldc = 2 * DIN;
      p.M = NTOK; p.N = 2 * DIN; p.K = DMODEL; p.Kp = DMODEL;
      gemm_mfma<EP_ABF16, 64><<<dim3(12, 13), 256, 0, stream>>>(p);
    }
    conv_silu<<<(NTOK * (DIN / 4) + 255) / 256, 256, 0, stream>>>(
        xz, cw + (size_t)i * DIN * 4, cb + (size_t)i * DIN, xic, xicb);
    {
      GemmP p = z;
      p.Abf = xicb; p.lda = DIN;
      p.Bbf = xpwb + (size_t)i * 56 * DIN; p.ldb = DIN;
      p.C = dbl; p.ldc = 56;
      p.M = NTOK; p.N = 56; p.K = DIN; p.Kp = DIN;
      gemm_mfma<EP_ABF16 | EP_BBF16, 64><<<dim3(1, 13), 256, 0, stream>>>(p);
    }
    scan_fused<<<384, 256, 0, stream>>>(dbl, xic, xz, dpw + (size_t)i * DIN * 24,
                                        dpb + (size_t)i * DIN,
                                        alog + (size_t)i * DIN * 16,
                                        Dp + (size_t)i * DIN, ymb);
    if (useBW) {
      GemmP p = z;
      p.Abf = ymb; p.lda = DIN;
      p.Bbf = opwb + (size_t)i * DMODEL * DIN; p.ldb = DIN;
      p.C = h; p.ldc = DMODEL;
      p.M = NTOK; p.N = DMODEL; p.K = DIN; p.Kp = DIN;
      gemm_mfma<EP_ABF16 | EP_BBF16, 64><<<dim3(3, 13), 256, 0, stream>>>(p);
    } else {
      GemmP p = z;
      p.Abf = ymb; p.lda = DIN;
      p.B = opw + (size_t)i * DMODEL * DIN; p.ldb = DIN;
      p.C = h; p.ldc = DMODEL;
      p.M = NTOK; p.N = DMODEL; p.K = DIN; p.Kp = DIN;
      gemm_mfma<EP_ABF16, 64><<<dim3(3, 13), 256, 0, stream>>>(p);
    }
  }

  final_kernel<<<NTOK, 64, 0, stream>>>(h, res, nfw, nfb, n2w, n2b, out);
}